// Round 1
// baseline (1836.900 us; speedup 1.0000x reference)
//
#include <hip/hip_runtime.h>
#include <math.h>

#define BN_EPS 1e-5f

// ---------------------------------------------------------------------------
// deg counting: float atomic increments (exact up to 2^24), into dinv buffer
// ---------------------------------------------------------------------------
__global__ __launch_bounds__(256) void deg_count_k(const int* __restrict__ dst,
                                                   float* __restrict__ deg, int E) {
    int e = blockIdx.x * 256 + threadIdx.x;
    if (e < E) atomicAdd(&deg[dst[e]], 1.0f);
}

// dinv[i] = rsqrt(deg[i] + 1)  (self loop), in place
__global__ __launch_bounds__(256) void dinv_k(float* __restrict__ buf, int N) {
    int i = blockIdx.x * 256 + threadIdx.x;
    if (i < N) buf[i] = rsqrtf(buf[i] + 1.0f);
}

// ---------------------------------------------------------------------------
// GEMM1: h1 = [uY | X] @ W1   (M=N nodes, K=192, Ncols=128)
// epilogue: h1 written; out1 initialized with self-loop h1*dinv^2
// tile: 64 nodes x 128 cols per block, K-chunks of 16, acc[4][8]/thread
// ---------------------------------------------------------------------------
__global__ __launch_bounds__(256) void gemm1_k(
    const float* __restrict__ uY, const float* __restrict__ X,
    const float* __restrict__ W1, const float* __restrict__ dinv,
    float* __restrict__ h1, float* __restrict__ out1, int N) {
    __shared__ float As[64][17];    // [node][k] padded
    __shared__ float Bs[16][128];   // [k][col]
    const int t  = threadIdx.x;
    const int nb = blockIdx.x * 64;
    const int tn = t & 15;          // node group (4 nodes)
    const int tc = t >> 4;          // col group  (8 cols)

    float acc[4][8];
#pragma unroll
    for (int i = 0; i < 4; ++i)
#pragma unroll
        for (int j = 0; j < 8; ++j) acc[i][j] = 0.0f;

    for (int k0 = 0; k0 < 192; k0 += 16) {
        // stage A: 64x16, thread loads 4 contiguous k's for one node
        {
            int l = t * 4;
            int an = l >> 4;        // node within tile
            int ak = l & 15;        // k within chunk (multiple of 4)
            int node = nb + an;
            float4 av = make_float4(0.f, 0.f, 0.f, 0.f);
            if (node < N) {
                if (k0 < 64) av = *(const float4*)(uY + (size_t)node * 64 + (k0 + ak));
                else         av = *(const float4*)(X  + (size_t)node * 128 + (k0 - 64 + ak));
            }
            As[an][ak + 0] = av.x; As[an][ak + 1] = av.y;
            As[an][ak + 2] = av.z; As[an][ak + 3] = av.w;
        }
        // stage B: 16x128, two float4 loads per thread
        {
            int l = t * 4;
            int bk = l >> 7, bj = l & 127;
            *(float4*)&Bs[bk][bj] = *(const float4*)(W1 + (size_t)(k0 + bk) * 128 + bj);
            int l2 = l + 1024;
            bk = l2 >> 7; bj = l2 & 127;
            *(float4*)&Bs[bk][bj] = *(const float4*)(W1 + (size_t)(k0 + bk) * 128 + bj);
        }
        __syncthreads();
#pragma unroll
        for (int kk = 0; kk < 16; ++kk) {
            float areg[4];
#pragma unroll
            for (int i = 0; i < 4; ++i) areg[i] = As[tn * 4 + i][kk];
            float breg[8];
            *(float4*)&breg[0] = *(const float4*)&Bs[kk][tc * 8];
            *(float4*)&breg[4] = *(const float4*)&Bs[kk][tc * 8 + 4];
#pragma unroll
            for (int i = 0; i < 4; ++i)
#pragma unroll
                for (int j = 0; j < 8; ++j)
                    acc[i][j] = fmaf(areg[i], breg[j], acc[i][j]);
        }
        __syncthreads();
    }

#pragma unroll
    for (int i = 0; i < 4; ++i) {
        int node = nb + tn * 4 + i;
        if (node >= N) continue;
        float dv = dinv[node];
        float d2 = dv * dv;
        float* hp = h1   + (size_t)node * 128 + tc * 8;
        float* op = out1 + (size_t)node * 128 + tc * 8;
        float4 v0 = make_float4(acc[i][0], acc[i][1], acc[i][2], acc[i][3]);
        float4 v1 = make_float4(acc[i][4], acc[i][5], acc[i][6], acc[i][7]);
        *(float4*)hp       = v0;
        *(float4*)(hp + 4) = v1;
        float4 w0 = make_float4(v0.x * d2, v0.y * d2, v0.z * d2, v0.w * d2);
        float4 w1 = make_float4(v1.x * d2, v1.y * d2, v1.z * d2, v1.w * d2);
        *(float4*)op       = w0;
        *(float4*)(op + 4) = w1;
    }
}

// ---------------------------------------------------------------------------
// aggregate1: one wave per edge; lane handles 2 channels (float2)
// out1[dst] += h1[src] * dinv[src]*dinv[dst]
// ---------------------------------------------------------------------------
__global__ __launch_bounds__(256) void agg1_k(
    const int* __restrict__ src, const int* __restrict__ dst,
    const float* __restrict__ dinv, const float* __restrict__ h1,
    float* __restrict__ out1, int E) {
    int e = blockIdx.x * 4 + (threadIdx.x >> 6);
    if (e >= E) return;
    int lane = threadIdx.x & 63;
    int s = src[e], d = dst[e];
    float norm = dinv[s] * dinv[d];
    float2 v = *(const float2*)(h1 + (size_t)s * 128 + lane * 2);
    float* op = out1 + (size_t)d * 128 + lane * 2;
    atomicAdd(op,     v.x * norm);
    atomicAdd(op + 1, v.y * norm);
}

// ---------------------------------------------------------------------------
// BN1 stats: per-channel sum & sumsq over nodes
// thread t: channel-quad c4=t&31, row-phase r=t>>5 (8 rows per block-iter)
// ---------------------------------------------------------------------------
__global__ __launch_bounds__(256) void bn1_stats_k(const float* __restrict__ out1,
                                                   float* __restrict__ stats, int N) {
    __shared__ float4 ssum[256];
    __shared__ float4 ssq[256];
    int t = threadIdx.x;
    int c4 = t & 31, r = t >> 5;
    float4 sum = make_float4(0.f, 0.f, 0.f, 0.f);
    float4 sq  = make_float4(0.f, 0.f, 0.f, 0.f);
    for (int n = blockIdx.x * 8 + r; n < N; n += gridDim.x * 8) {
        float4 v = *(const float4*)(out1 + (size_t)n * 128 + c4 * 4);
        sum.x += v.x; sum.y += v.y; sum.z += v.z; sum.w += v.w;
        sq.x += v.x * v.x; sq.y += v.y * v.y; sq.z += v.z * v.z; sq.w += v.w * v.w;
    }
    ssum[t] = sum; ssq[t] = sq;
    __syncthreads();
    for (int sft = 128; sft >= 32; sft >>= 1) {
        if (t < sft) {
            ssum[t].x += ssum[t + sft].x; ssum[t].y += ssum[t + sft].y;
            ssum[t].z += ssum[t + sft].z; ssum[t].w += ssum[t + sft].w;
            ssq[t].x  += ssq[t + sft].x;  ssq[t].y  += ssq[t + sft].y;
            ssq[t].z  += ssq[t + sft].z;  ssq[t].w  += ssq[t + sft].w;
        }
        __syncthreads();
    }
    if (t < 32) {
        float4 a = ssum[t], b = ssq[t];
        atomicAdd(&stats[t * 4 + 0], a.x); atomicAdd(&stats[t * 4 + 1], a.y);
        atomicAdd(&stats[t * 4 + 2], a.z); atomicAdd(&stats[t * 4 + 3], a.w);
        atomicAdd(&stats[128 + t * 4 + 0], b.x); atomicAdd(&stats[128 + t * 4 + 1], b.y);
        atomicAdd(&stats[128 + t * 4 + 2], b.z); atomicAdd(&stats[128 + t * 4 + 3], b.w);
    }
}

// bn1[c] = a (scale), bn1[128+c] = c (shift);  BN(x) = a*x + c
__global__ void bn1_final_k(const float* __restrict__ stats,
                            const float* __restrict__ gamma1,
                            const float* __restrict__ beta1,
                            float* __restrict__ bn1, float invN) {
    int c = threadIdx.x;
    float mean = stats[c] * invN;
    float var  = stats[128 + c] * invN - mean * mean;
    float a = gamma1[c] * rsqrtf(var + BN_EPS);
    bn1[c] = a;
    bn1[128 + c] = beta1[c] - mean * a;
}

// ---------------------------------------------------------------------------
// GEMM2 fused: y = relu(BN1(out1)); h2 = y @ W2 [N,2]; out2 init self-loop
// one wave per node; lane handles channels {lane, lane+64}
// ---------------------------------------------------------------------------
__global__ __launch_bounds__(256) void gemm2_k(
    const float* __restrict__ out1, const float* __restrict__ bn1,
    const float* __restrict__ W2, const float* __restrict__ dinv,
    float* __restrict__ h2, float* __restrict__ out2, int N) {
    int node = blockIdx.x * 4 + (threadIdx.x >> 6);
    if (node >= N) return;
    int lane = threadIdx.x & 63;
    float v0 = out1[(size_t)node * 128 + lane];
    float v1 = out1[(size_t)node * 128 + lane + 64];
    float y0 = fmaxf(fmaf(bn1[lane],      v0, bn1[128 + lane]),      0.f);
    float y1 = fmaxf(fmaf(bn1[lane + 64], v1, bn1[128 + lane + 64]), 0.f);
    float2 wl = *(const float2*)(W2 + lane * 2);
    float2 wh = *(const float2*)(W2 + (lane + 64) * 2);
    float acc0 = y0 * wl.x + y1 * wh.x;
    float acc1 = y0 * wl.y + y1 * wh.y;
    for (int off = 32; off; off >>= 1) {
        acc0 += __shfl_xor(acc0, off);
        acc1 += __shfl_xor(acc1, off);
    }
    if (lane == 0) {
        float dv = dinv[node];
        float d2 = dv * dv;
        *(float2*)(h2 + (size_t)node * 2)   = make_float2(acc0, acc1);
        *(float2*)(out2 + (size_t)node * 2) = make_float2(acc0 * d2, acc1 * d2);
    }
}

// aggregate2: thread per edge, 2 channels
__global__ __launch_bounds__(256) void agg2_k(
    const int* __restrict__ src, const int* __restrict__ dst,
    const float* __restrict__ dinv, const float* __restrict__ h2,
    float* __restrict__ out2, int E) {
    int e = blockIdx.x * 256 + threadIdx.x;
    if (e >= E) return;
    int s = src[e], d = dst[e];
    float norm = dinv[s] * dinv[d];
    float2 v = *(const float2*)(h2 + (size_t)s * 2);
    atomicAdd(&out2[(size_t)d * 2],     v.x * norm);
    atomicAdd(&out2[(size_t)d * 2 + 1], v.y * norm);
}

// BN2 stats: 4 scalars {sum0,sum1,sq0,sq1}
__global__ __launch_bounds__(256) void bn2_stats_k(const float* __restrict__ out2,
                                                   float* __restrict__ stats, int N) {
    __shared__ float4 red[256];
    int t = threadIdx.x;
    float4 acc = make_float4(0.f, 0.f, 0.f, 0.f);
    for (int n = blockIdx.x * 256 + t; n < N; n += gridDim.x * 256) {
        float2 v = *(const float2*)(out2 + (size_t)n * 2);
        acc.x += v.x; acc.y += v.y; acc.z += v.x * v.x; acc.w += v.y * v.y;
    }
    red[t] = acc;
    __syncthreads();
    for (int s = 128; s; s >>= 1) {
        if (t < s) {
            red[t].x += red[t + s].x; red[t].y += red[t + s].y;
            red[t].z += red[t + s].z; red[t].w += red[t + s].w;
        }
        __syncthreads();
    }
    if (t == 0) {
        atomicAdd(&stats[0], red[0].x); atomicAdd(&stats[1], red[0].y);
        atomicAdd(&stats[2], red[0].z); atomicAdd(&stats[3], red[0].w);
    }
}

// final: BN2 (inline from stats) + softmax over 2 classes
__global__ __launch_bounds__(256) void final_k(
    const float* __restrict__ out2, const float* __restrict__ stats,
    const float* __restrict__ gamma2, const float* __restrict__ beta2,
    float* __restrict__ outp, int N, float invN) {
    int i = blockIdx.x * 256 + threadIdx.x;
    if (i >= N) return;
    float m0 = stats[0] * invN, m1 = stats[1] * invN;
    float var0 = stats[2] * invN - m0 * m0;
    float var1 = stats[3] * invN - m1 * m1;
    float a0 = gamma2[0] * rsqrtf(var0 + BN_EPS);
    float a1 = gamma2[1] * rsqrtf(var1 + BN_EPS);
    float c0 = beta2[0] - m0 * a0;
    float c1 = beta2[1] - m1 * a1;
    float2 v = *(const float2*)(out2 + (size_t)i * 2);
    float y0 = fmaf(a0, v.x, c0);
    float y1 = fmaf(a1, v.y, c1);
    float mx = fmaxf(y0, y1);
    float e0 = expf(y0 - mx), e1 = expf(y1 - mx);
    float inv = 1.f / (e0 + e1);
    *(float2*)(outp + (size_t)i * 2) = make_float2(e0 * inv, e1 * inv);
}

// ---------------------------------------------------------------------------
extern "C" void kernel_launch(void* const* d_in, const int* in_sizes, int n_in,
                              void* d_out, int out_size, void* d_ws, size_t ws_size,
                              hipStream_t stream) {
    const int*   edge   = (const int*)d_in[0];
    const float* X      = (const float*)d_in[1];
    const float* uY     = (const float*)d_in[2];
    const float* W1     = (const float*)d_in[3];
    // d_in[4] = b1: cancels under BatchNorm (mean subtraction) -- skipped
    const float* W2     = (const float*)d_in[5];
    // d_in[6] = b2: cancels under BatchNorm -- skipped
    const float* gamma1 = (const float*)d_in[7];
    const float* beta1  = (const float*)d_in[8];
    const float* gamma2 = (const float*)d_in[9];
    const float* beta2  = (const float*)d_in[10];

    const int E = in_sizes[0] / 2;
    const int N = in_sizes[1] / 128;
    const int* srcI = edge;
    const int* dstI = edge + E;

    // workspace layout (floats): h1[N*128] out1[N*128] dinv[N] h2[2N] out2[2N]
    //                            stats1[256] bn1[256] stats2[4]   (~104.4 MB)
    float* h1     = (float*)d_ws;
    float* out1   = h1 + (size_t)N * 128;
    float* dinv   = out1 + (size_t)N * 128;
    float* h2     = dinv + N;
    float* out2   = h2 + (size_t)N * 2;
    float* stats1 = out2 + (size_t)N * 2;
    float* bn1    = stats1 + 256;
    float* stats2 = bn1 + 256;

    hipMemsetAsync(dinv,   0, (size_t)N * sizeof(float), stream);
    hipMemsetAsync(stats1, 0, 256 * sizeof(float), stream);
    hipMemsetAsync(stats2, 0, 4 * sizeof(float), stream);

    deg_count_k<<<(E + 255) / 256, 256, 0, stream>>>(dstI, dinv, E);
    dinv_k<<<(N + 255) / 256, 256, 0, stream>>>(dinv, N);
    gemm1_k<<<(N + 63) / 64, 256, 0, stream>>>(uY, X, W1, dinv, h1, out1, N);
    agg1_k<<<(E + 3) / 4, 256, 0, stream>>>(srcI, dstI, dinv, h1, out1, E);
    bn1_stats_k<<<512, 256, 0, stream>>>(out1, stats1, N);
    bn1_final_k<<<1, 128, 0, stream>>>(stats1, gamma1, beta1, bn1, 1.0f / N);
    gemm2_k<<<(N + 3) / 4, 256, 0, stream>>>(out1, bn1, W2, dinv, h2, out2, N);
    agg2_k<<<(E + 255) / 256, 256, 0, stream>>>(srcI, dstI, dinv, h2, out2, E);
    bn2_stats_k<<<256, 256, 0, stream>>>(out2, stats2, N);
    final_k<<<(N + 255) / 256, 256, 0, stream>>>(out2, stats2, gamma2, beta2,
                                                 (float*)d_out, N, 1.0f / N);
}

// Round 2
// 580.901 us; speedup vs baseline: 3.1622x; 3.1622x over previous
//
#include <hip/hip_runtime.h>
#include <math.h>

#define BN_EPS 1e-5f

// ---------------------------------------------------------------------------
// degree counting: int atomic increments into cnt[]
// ---------------------------------------------------------------------------
__global__ __launch_bounds__(256) void deg_count_k(const int* __restrict__ dst,
                                                   int* __restrict__ cnt, int E) {
    int e = blockIdx.x * 256 + threadIdx.x;
    if (e < E) atomicAdd(&cnt[dst[e]], 1);
}

// dinv[i] = rsqrt(cnt[i] + 1)  (self loop)
__global__ __launch_bounds__(256) void dinv_k(const int* __restrict__ cnt,
                                              float* __restrict__ dinv, int N) {
    int i = blockIdx.x * 256 + threadIdx.x;
    if (i < N) dinv[i] = rsqrtf((float)cnt[i] + 1.0f);
}

// ---------------------------------------------------------------------------
// exclusive scan of cnt[] -> offs[]  (3 kernels; N <= 256*1024)
// ---------------------------------------------------------------------------
__global__ __launch_bounds__(256) void scan_a_k(const int* __restrict__ cnt,
                                                int* __restrict__ offs,
                                                int* __restrict__ blksum, int N) {
    __shared__ int s[256];
    int t = threadIdx.x;
    int base = blockIdx.x * 1024 + t * 4;
    int v0 = 0, v1 = 0, v2 = 0, v3 = 0;
    if (base + 3 < N) {
        int4 q = *(const int4*)(cnt + base);
        v0 = q.x; v1 = q.y; v2 = q.z; v3 = q.w;
    } else {
        if (base     < N) v0 = cnt[base];
        if (base + 1 < N) v1 = cnt[base + 1];
        if (base + 2 < N) v2 = cnt[base + 2];
        if (base + 3 < N) v3 = cnt[base + 3];
    }
    int tsum = v0 + v1 + v2 + v3;
    s[t] = tsum;
    __syncthreads();
    for (int off = 1; off < 256; off <<= 1) {
        int x = (t >= off) ? s[t - off] : 0;
        __syncthreads();
        s[t] += x;
        __syncthreads();
    }
    int texcl = s[t] - tsum;
    if (t == 255) blksum[blockIdx.x] = s[255];
    int e0 = texcl, e1 = e0 + v0, e2 = e1 + v1, e3 = e2 + v2;
    if (base     < N) offs[base]     = e0;
    if (base + 1 < N) offs[base + 1] = e1;
    if (base + 2 < N) offs[base + 2] = e2;
    if (base + 3 < N) offs[base + 3] = e3;
}

__global__ __launch_bounds__(256) void scan_b_k(int* __restrict__ blksum, int NB) {
    __shared__ int s[256];
    int t = threadIdx.x;
    int v = (t < NB) ? blksum[t] : 0;
    s[t] = v;
    __syncthreads();
    for (int off = 1; off < 256; off <<= 1) {
        int x = (t >= off) ? s[t - off] : 0;
        __syncthreads();
        s[t] += x;
        __syncthreads();
    }
    if (t < NB) blksum[t] = s[t] - v;   // exclusive
}

__global__ __launch_bounds__(256) void scan_c_k(int* __restrict__ offs,
                                                const int* __restrict__ blksum, int N) {
    int i = blockIdx.x * 256 + threadIdx.x;
    if (i < N) offs[i] += blksum[blockIdx.x >> 2];
}

// scatter edges into dst-grouped CSR
__global__ __launch_bounds__(256) void scatter_k(
    const int* __restrict__ src, const int* __restrict__ dst,
    const int* __restrict__ offs, int* __restrict__ cur,
    int* __restrict__ csr, int E) {
    int e = blockIdx.x * 256 + threadIdx.x;
    if (e >= E) return;
    int d = dst[e];
    int pos = offs[d] + atomicAdd(&cur[d], 1);
    csr[pos] = src[e];
}

// ---------------------------------------------------------------------------
// GEMM1: h1s = ([uY | X] @ W1) * dinv[node]   (M=N, K=192, cols=128)
// ---------------------------------------------------------------------------
__global__ __launch_bounds__(256) void gemm1_k(
    const float* __restrict__ uY, const float* __restrict__ X,
    const float* __restrict__ W1, const float* __restrict__ dinv,
    float* __restrict__ h1s, int N) {
    __shared__ float As[64][17];
    __shared__ float Bs[16][128];
    const int t  = threadIdx.x;
    const int nb = blockIdx.x * 64;
    const int tn = t & 15;
    const int tc = t >> 4;

    float acc[4][8];
#pragma unroll
    for (int i = 0; i < 4; ++i)
#pragma unroll
        for (int j = 0; j < 8; ++j) acc[i][j] = 0.0f;

    for (int k0 = 0; k0 < 192; k0 += 16) {
        {
            int l = t * 4;
            int an = l >> 4, ak = l & 15;
            int node = nb + an;
            float4 av = make_float4(0.f, 0.f, 0.f, 0.f);
            if (node < N) {
                if (k0 < 64) av = *(const float4*)(uY + (size_t)node * 64 + (k0 + ak));
                else         av = *(const float4*)(X  + (size_t)node * 128 + (k0 - 64 + ak));
            }
            As[an][ak + 0] = av.x; As[an][ak + 1] = av.y;
            As[an][ak + 2] = av.z; As[an][ak + 3] = av.w;
        }
        {
            int l = t * 4;
            int bk = l >> 7, bj = l & 127;
            *(float4*)&Bs[bk][bj] = *(const float4*)(W1 + (size_t)(k0 + bk) * 128 + bj);
            int l2 = l + 1024;
            bk = l2 >> 7; bj = l2 & 127;
            *(float4*)&Bs[bk][bj] = *(const float4*)(W1 + (size_t)(k0 + bk) * 128 + bj);
        }
        __syncthreads();
#pragma unroll
        for (int kk = 0; kk < 16; ++kk) {
            float areg[4];
#pragma unroll
            for (int i = 0; i < 4; ++i) areg[i] = As[tn * 4 + i][kk];
            float breg[8];
            *(float4*)&breg[0] = *(const float4*)&Bs[kk][tc * 8];
            *(float4*)&breg[4] = *(const float4*)&Bs[kk][tc * 8 + 4];
#pragma unroll
            for (int i = 0; i < 4; ++i)
#pragma unroll
                for (int j = 0; j < 8; ++j)
                    acc[i][j] = fmaf(areg[i], breg[j], acc[i][j]);
        }
        __syncthreads();
    }

#pragma unroll
    for (int i = 0; i < 4; ++i) {
        int node = nb + tn * 4 + i;
        if (node >= N) continue;
        float dv = dinv[node];
        float* hp = h1s + (size_t)node * 128 + tc * 8;
        float4 v0 = make_float4(acc[i][0] * dv, acc[i][1] * dv, acc[i][2] * dv, acc[i][3] * dv);
        float4 v1 = make_float4(acc[i][4] * dv, acc[i][5] * dv, acc[i][6] * dv, acc[i][7] * dv);
        *(float4*)hp       = v0;
        *(float4*)(hp + 4) = v1;
    }
}

// ---------------------------------------------------------------------------
// aggregate1 by gather: one wave per node, lane = 2 channels
// out1[d] = dinv[d] * (h1s[d] + sum_{e in CSR[d]} h1s[src_e])
// ---------------------------------------------------------------------------
__global__ __launch_bounds__(256) void agg1_gather_k(
    const int* __restrict__ csr, const int* __restrict__ offs,
    const int* __restrict__ cnt, const float* __restrict__ dinv,
    const float* __restrict__ h1s, float* __restrict__ out1, int N) {
    int node = blockIdx.x * 4 + (threadIdx.x >> 6);
    if (node >= N) return;
    int lane = threadIdx.x & 63;
    int beg = offs[node], num = cnt[node];
    float2 acc = *(const float2*)(h1s + (size_t)node * 128 + lane * 2);
    int i = 0;
    for (; i + 1 < num; i += 2) {
        int s0 = csr[beg + i];
        int s1 = csr[beg + i + 1];
        float2 v0 = *(const float2*)(h1s + (size_t)s0 * 128 + lane * 2);
        float2 v1 = *(const float2*)(h1s + (size_t)s1 * 128 + lane * 2);
        acc.x += v0.x + v1.x;
        acc.y += v0.y + v1.y;
    }
    if (i < num) {
        int s0 = csr[beg + i];
        float2 v0 = *(const float2*)(h1s + (size_t)s0 * 128 + lane * 2);
        acc.x += v0.x;
        acc.y += v0.y;
    }
    float dd = dinv[node];
    acc.x *= dd; acc.y *= dd;
    *(float2*)(out1 + (size_t)node * 128 + lane * 2) = acc;
}

// ---------------------------------------------------------------------------
// BN1 stats: per-channel sum & sumsq
// ---------------------------------------------------------------------------
__global__ __launch_bounds__(256) void bn1_stats_k(const float* __restrict__ out1,
                                                   float* __restrict__ stats, int N) {
    __shared__ float4 ssum[256];
    __shared__ float4 ssq[256];
    int t = threadIdx.x;
    int c4 = t & 31, r = t >> 5;
    float4 sum = make_float4(0.f, 0.f, 0.f, 0.f);
    float4 sq  = make_float4(0.f, 0.f, 0.f, 0.f);
    for (int n = blockIdx.x * 8 + r; n < N; n += gridDim.x * 8) {
        float4 v = *(const float4*)(out1 + (size_t)n * 128 + c4 * 4);
        sum.x += v.x; sum.y += v.y; sum.z += v.z; sum.w += v.w;
        sq.x += v.x * v.x; sq.y += v.y * v.y; sq.z += v.z * v.z; sq.w += v.w * v.w;
    }
    ssum[t] = sum; ssq[t] = sq;
    __syncthreads();
    for (int sft = 128; sft >= 32; sft >>= 1) {
        if (t < sft) {
            ssum[t].x += ssum[t + sft].x; ssum[t].y += ssum[t + sft].y;
            ssum[t].z += ssum[t + sft].z; ssum[t].w += ssum[t + sft].w;
            ssq[t].x  += ssq[t + sft].x;  ssq[t].y  += ssq[t + sft].y;
            ssq[t].z  += ssq[t + sft].z;  ssq[t].w  += ssq[t + sft].w;
        }
        __syncthreads();
    }
    if (t < 32) {
        float4 a = ssum[t], b = ssq[t];
        atomicAdd(&stats[t * 4 + 0], a.x); atomicAdd(&stats[t * 4 + 1], a.y);
        atomicAdd(&stats[t * 4 + 2], a.z); atomicAdd(&stats[t * 4 + 3], a.w);
        atomicAdd(&stats[128 + t * 4 + 0], b.x); atomicAdd(&stats[128 + t * 4 + 1], b.y);
        atomicAdd(&stats[128 + t * 4 + 2], b.z); atomicAdd(&stats[128 + t * 4 + 3], b.w);
    }
}

__global__ void bn1_final_k(const float* __restrict__ stats,
                            const float* __restrict__ gamma1,
                            const float* __restrict__ beta1,
                            float* __restrict__ bn1, float invN) {
    int c = threadIdx.x;
    float mean = stats[c] * invN;
    float var  = stats[128 + c] * invN - mean * mean;
    float a = gamma1[c] * rsqrtf(var + BN_EPS);
    bn1[c] = a;
    bn1[128 + c] = beta1[c] - mean * a;
}

// ---------------------------------------------------------------------------
// GEMM2 fused: y = relu(BN1(out1)); h2s = (y @ W2) * dinv[node]
// ---------------------------------------------------------------------------
__global__ __launch_bounds__(256) void gemm2_k(
    const float* __restrict__ out1, const float* __restrict__ bn1,
    const float* __restrict__ W2, const float* __restrict__ dinv,
    float* __restrict__ h2s, int N) {
    int node = blockIdx.x * 4 + (threadIdx.x >> 6);
    if (node >= N) return;
    int lane = threadIdx.x & 63;
    float v0 = out1[(size_t)node * 128 + lane];
    float v1 = out1[(size_t)node * 128 + lane + 64];
    float y0 = fmaxf(fmaf(bn1[lane],      v0, bn1[128 + lane]),      0.f);
    float y1 = fmaxf(fmaf(bn1[lane + 64], v1, bn1[128 + lane + 64]), 0.f);
    float2 wl = *(const float2*)(W2 + lane * 2);
    float2 wh = *(const float2*)(W2 + (lane + 64) * 2);
    float acc0 = y0 * wl.x + y1 * wh.x;
    float acc1 = y0 * wl.y + y1 * wh.y;
    for (int off = 32; off; off >>= 1) {
        acc0 += __shfl_xor(acc0, off);
        acc1 += __shfl_xor(acc1, off);
    }
    if (lane == 0) {
        float dv = dinv[node];
        *(float2*)(h2s + (size_t)node * 2) = make_float2(acc0 * dv, acc1 * dv);
    }
}

// aggregate2 by gather: one thread per node, both channels
__global__ __launch_bounds__(256) void agg2_gather_k(
    const int* __restrict__ csr, const int* __restrict__ offs,
    const int* __restrict__ cnt, const float* __restrict__ dinv,
    const float* __restrict__ h2s, float* __restrict__ out2, int N) {
    int node = blockIdx.x * 256 + threadIdx.x;
    if (node >= N) return;
    int beg = offs[node], num = cnt[node];
    float2 acc = *(const float2*)(h2s + (size_t)node * 2);
    for (int i = 0; i < num; ++i) {
        int s = csr[beg + i];
        float2 v = *(const float2*)(h2s + (size_t)s * 2);
        acc.x += v.x;
        acc.y += v.y;
    }
    float dd = dinv[node];
    *(float2*)(out2 + (size_t)node * 2) = make_float2(acc.x * dd, acc.y * dd);
}

// BN2 stats
__global__ __launch_bounds__(256) void bn2_stats_k(const float* __restrict__ out2,
                                                   float* __restrict__ stats, int N) {
    __shared__ float4 red[256];
    int t = threadIdx.x;
    float4 acc = make_float4(0.f, 0.f, 0.f, 0.f);
    for (int n = blockIdx.x * 256 + t; n < N; n += gridDim.x * 256) {
        float2 v = *(const float2*)(out2 + (size_t)n * 2);
        acc.x += v.x; acc.y += v.y; acc.z += v.x * v.x; acc.w += v.y * v.y;
    }
    red[t] = acc;
    __syncthreads();
    for (int s = 128; s; s >>= 1) {
        if (t < s) {
            red[t].x += red[t + s].x; red[t].y += red[t + s].y;
            red[t].z += red[t + s].z; red[t].w += red[t + s].w;
        }
        __syncthreads();
    }
    if (t == 0) {
        atomicAdd(&stats[0], red[0].x); atomicAdd(&stats[1], red[0].y);
        atomicAdd(&stats[2], red[0].z); atomicAdd(&stats[3], red[0].w);
    }
}

// final: BN2 + softmax(2)
__global__ __launch_bounds__(256) void final_k(
    const float* __restrict__ out2, const float* __restrict__ stats,
    const float* __restrict__ gamma2, const float* __restrict__ beta2,
    float* __restrict__ outp, int N, float invN) {
    int i = blockIdx.x * 256 + threadIdx.x;
    if (i >= N) return;
    float m0 = stats[0] * invN, m1 = stats[1] * invN;
    float var0 = stats[2] * invN - m0 * m0;
    float var1 = stats[3] * invN - m1 * m1;
    float a0 = gamma2[0] * rsqrtf(var0 + BN_EPS);
    float a1 = gamma2[1] * rsqrtf(var1 + BN_EPS);
    float c0 = beta2[0] - m0 * a0;
    float c1 = beta2[1] - m1 * a1;
    float2 v = *(const float2*)(out2 + (size_t)i * 2);
    float y0 = fmaf(a0, v.x, c0);
    float y1 = fmaf(a1, v.y, c1);
    float mx = fmaxf(y0, y1);
    float e0 = expf(y0 - mx), e1 = expf(y1 - mx);
    float inv = 1.f / (e0 + e1);
    *(float2*)(outp + (size_t)i * 2) = make_float2(e0 * inv, e1 * inv);
}

// ---------------------------------------------------------------------------
extern "C" void kernel_launch(void* const* d_in, const int* in_sizes, int n_in,
                              void* d_out, int out_size, void* d_ws, size_t ws_size,
                              hipStream_t stream) {
    const int*   edge   = (const int*)d_in[0];
    const float* X      = (const float*)d_in[1];
    const float* uY     = (const float*)d_in[2];
    const float* W1     = (const float*)d_in[3];
    // b1/b2 cancel under BatchNorm -- skipped
    const float* W2     = (const float*)d_in[5];
    const float* gamma1 = (const float*)d_in[7];
    const float* beta1  = (const float*)d_in[8];
    const float* gamma2 = (const float*)d_in[9];
    const float* beta2  = (const float*)d_in[10];

    const int E = in_sizes[0] / 2;
    const int N = in_sizes[1] / 128;
    const int* srcI = edge;
    const int* dstI = edge + E;

    // workspace layout (4B elems):
    // h1s[N*128] out1[N*128] dinv[N] h2s[2N] out2[2N] stats1[256] bn1[256]
    // stats2[4] pad[60] cnt[N] offs[N] cur[N] blksum[256] csr[E]   (~111 MB)
    float* h1s    = (float*)d_ws;
    float* out1   = h1s + (size_t)N * 128;
    float* dinv   = out1 + (size_t)N * 128;
    float* h2s    = dinv + N;
    float* out2   = h2s + (size_t)N * 2;
    float* stats1 = out2 + (size_t)N * 2;
    float* bn1    = stats1 + 256;
    float* stats2 = bn1 + 256;
    int*   cnt    = (int*)(stats2 + 64);
    int*   offs   = cnt + N;
    int*   cur    = offs + N;
    int*   blksum = cur + N;
    int*   csr    = blksum + 256;

    hipMemsetAsync(cnt,    0, (size_t)N * sizeof(int), stream);
    hipMemsetAsync(cur,    0, (size_t)N * sizeof(int), stream);
    hipMemsetAsync(stats1, 0, 256 * sizeof(float), stream);
    hipMemsetAsync(stats2, 0, 4 * sizeof(float), stream);

    const int NB = (N + 1023) / 1024;   // scan blocks (<= 256)

    deg_count_k<<<(E + 255) / 256, 256, 0, stream>>>(dstI, cnt, E);
    dinv_k<<<(N + 255) / 256, 256, 0, stream>>>(cnt, dinv, N);
    scan_a_k<<<NB, 256, 0, stream>>>(cnt, offs, blksum, N);
    scan_b_k<<<1, 256, 0, stream>>>(blksum, NB);
    scan_c_k<<<NB * 4, 256, 0, stream>>>(offs, blksum, N);
    scatter_k<<<(E + 255) / 256, 256, 0, stream>>>(srcI, dstI, offs, cur, csr, E);

    gemm1_k<<<(N + 63) / 64, 256, 0, stream>>>(uY, X, W1, dinv, h1s, N);
    agg1_gather_k<<<(N + 3) / 4, 256, 0, stream>>>(csr, offs, cnt, dinv, h1s, out1, N);
    bn1_stats_k<<<512, 256, 0, stream>>>(out1, stats1, N);
    bn1_final_k<<<1, 128, 0, stream>>>(stats1, gamma1, beta1, bn1, 1.0f / N);
    gemm2_k<<<(N + 3) / 4, 256, 0, stream>>>(out1, bn1, W2, dinv, h2s, N);
    agg2_gather_k<<<(N + 255) / 256, 256, 0, stream>>>(csr, offs, cnt, dinv, h2s, out2, N);
    bn2_stats_k<<<256, 256, 0, stream>>>(out2, stats2, N);
    final_k<<<(N + 255) / 256, 256, 0, stream>>>(out2, stats2, gamma2, beta2,
                                                 (float*)d_out, N, 1.0f / N);
}

// Round 6
// 519.126 us; speedup vs baseline: 3.5384x; 1.1190x over previous
//
#include <hip/hip_runtime.h>
#include <math.h>

#define BN_EPS 1e-5f

typedef __attribute__((ext_vector_type(8))) short short8v;
typedef __attribute__((ext_vector_type(4))) float f32x4;

__device__ __forceinline__ unsigned short f2bf(float x) {
    unsigned int u = __float_as_uint(x);
    u += 0x7FFFu + ((u >> 16) & 1u);     // RNE
    return (unsigned short)(u >> 16);
}
__device__ __forceinline__ float bf2f(unsigned int u16) {
    return __uint_as_float(u16 << 16);
}
__device__ __forceinline__ unsigned int pack2bf(float a, float b) {
    return (unsigned int)f2bf(a) | ((unsigned int)f2bf(b) << 16);
}

// ---------------------------------------------------------------------------
// degree counting (int4-vectorized edge reads)
// ---------------------------------------------------------------------------
__global__ __launch_bounds__(256) void deg_count_k(const int* __restrict__ dst,
                                                   int* __restrict__ cnt, int E) {
    int e4 = (blockIdx.x * 256 + threadIdx.x) * 4;
    if (e4 + 3 < E) {
        int4 d = *(const int4*)(dst + e4);
        atomicAdd(&cnt[d.x], 1); atomicAdd(&cnt[d.y], 1);
        atomicAdd(&cnt[d.z], 1); atomicAdd(&cnt[d.w], 1);
    } else {
        for (int e = e4; e < E; ++e) atomicAdd(&cnt[dst[e]], 1);
    }
}

// ---------------------------------------------------------------------------
// scan: exclusive prefix of cnt -> offs ; also emits dinv = rsqrt(cnt+1)
// ---------------------------------------------------------------------------
__global__ __launch_bounds__(256) void scan_a_k(const int* __restrict__ cnt,
                                                int* __restrict__ offs,
                                                int* __restrict__ blksum,
                                                float* __restrict__ dinv, int N) {
    __shared__ int s[256];
    int t = threadIdx.x;
    int base = blockIdx.x * 1024 + t * 4;
    int v0 = 0, v1 = 0, v2 = 0, v3 = 0;
    if (base + 3 < N) {
        int4 q = *(const int4*)(cnt + base);
        v0 = q.x; v1 = q.y; v2 = q.z; v3 = q.w;
    } else {
        if (base     < N) v0 = cnt[base];
        if (base + 1 < N) v1 = cnt[base + 1];
        if (base + 2 < N) v2 = cnt[base + 2];
        if (base + 3 < N) v3 = cnt[base + 3];
    }
    if (base     < N) dinv[base]     = rsqrtf((float)v0 + 1.0f);
    if (base + 1 < N) dinv[base + 1] = rsqrtf((float)v1 + 1.0f);
    if (base + 2 < N) dinv[base + 2] = rsqrtf((float)v2 + 1.0f);
    if (base + 3 < N) dinv[base + 3] = rsqrtf((float)v3 + 1.0f);
    int tsum = v0 + v1 + v2 + v3;
    s[t] = tsum;
    __syncthreads();
    for (int off = 1; off < 256; off <<= 1) {
        int x = (t >= off) ? s[t - off] : 0;
        __syncthreads();
        s[t] += x;
        __syncthreads();
    }
    int texcl = s[t] - tsum;
    if (t == 255) blksum[blockIdx.x] = s[255];
    int e0 = texcl, e1 = e0 + v0, e2 = e1 + v1, e3 = e2 + v2;
    if (base     < N) offs[base]     = e0;
    if (base + 1 < N) offs[base + 1] = e1;
    if (base + 2 < N) offs[base + 2] = e2;
    if (base + 3 < N) offs[base + 3] = e3;
}

__global__ __launch_bounds__(256) void scan_b_k(int* __restrict__ blksum, int NB) {
    __shared__ int s[256];
    int t = threadIdx.x;
    int v = (t < NB) ? blksum[t] : 0;
    s[t] = v;
    __syncthreads();
    for (int off = 1; off < 256; off <<= 1) {
        int x = (t >= off) ? s[t - off] : 0;
        __syncthreads();
        s[t] += x;
        __syncthreads();
    }
    if (t < NB) blksum[t] = s[t] - v;
}

__global__ __launch_bounds__(256) void scan_c_k(int* __restrict__ offs,
                                                const int* __restrict__ blksum, int N) {
    int i = blockIdx.x * 256 + threadIdx.x;
    if (i < N) offs[i] += blksum[blockIdx.x >> 2];
}

// scatter edges into dst-grouped CSR (int4-vectorized)
__global__ __launch_bounds__(256) void scatter_k(
    const int* __restrict__ src, const int* __restrict__ dst,
    const int* __restrict__ offs, int* __restrict__ cur,
    int* __restrict__ csr, int E) {
    int e4 = (blockIdx.x * 256 + threadIdx.x) * 4;
    if (e4 + 3 < E) {
        int4 sv = *(const int4*)(src + e4);
        int4 dv = *(const int4*)(dst + e4);
        csr[offs[dv.x] + atomicAdd(&cur[dv.x], 1)] = sv.x;
        csr[offs[dv.y] + atomicAdd(&cur[dv.y], 1)] = sv.y;
        csr[offs[dv.z] + atomicAdd(&cur[dv.z], 1)] = sv.z;
        csr[offs[dv.w] + atomicAdd(&cur[dv.w], 1)] = sv.w;
    } else {
        for (int e = e4; e < E; ++e) {
            int d = dst[e];
            csr[offs[d] + atomicAdd(&cur[d], 1)] = src[e];
        }
    }
}

// ---------------------------------------------------------------------------
// W1 cast: [192][128] f32 -> transposed hi/lo bf16 [128 cols][192 k]
// ---------------------------------------------------------------------------
__global__ __launch_bounds__(256) void w1cast_k(const float* __restrict__ W1,
                                                unsigned short* __restrict__ Whi,
                                                unsigned short* __restrict__ Wlo) {
    int t = blockIdx.x * 256 + threadIdx.x;   // 0 .. 192*128-1
    if (t >= 192 * 128) return;
    int k = t >> 7, c = t & 127;
    float v = W1[t];
    unsigned short hi = f2bf(v);
    float lo = v - bf2f(hi);
    Whi[c * 192 + k] = hi;
    Wlo[c * 192 + k] = f2bf(lo);
}

// ---------------------------------------------------------------------------
// GEMM1 (MFMA, split-bf16): h1s = ([uY | X] @ W1) * dinv[node],  bf16 out
// block: 256 thr = 4 waves, tile BM=128 x BN=128, BK=64 (3 chunks = K 192)
// wave w owns rows [w*32, w*32+32): 2 m-frags x 8 n-frags of 16x16x32 MFMA
// LDS tiles XOR-swizzled: byte ^= (row&7)<<4
// ---------------------------------------------------------------------------
__global__ __launch_bounds__(256) void gemm1_mfma_k(
    const float* __restrict__ uY, const float* __restrict__ X,
    const unsigned short* __restrict__ Whi, const unsigned short* __restrict__ Wlo,
    const float* __restrict__ dinv, unsigned short* __restrict__ h1s, int N) {
    __shared__ unsigned short Ah[128 * 64];
    __shared__ unsigned short Al[128 * 64];
    __shared__ unsigned short Bh[128 * 64];
    __shared__ unsigned short Bl[128 * 64];
    __shared__ float dvs[128];
    const int t = threadIdx.x;
    const int wave = t >> 6, lane = t & 63;
    const int lr = lane & 15, lg = lane >> 4;
    const int nb = blockIdx.x * 128;

    if (t < 128) {
        int node = nb + t;
        dvs[t] = (node < N) ? dinv[node] : 0.0f;
    }

    f32x4 acc[2][8];
    for (int i = 0; i < 2; ++i)
        for (int j = 0; j < 8; ++j)
            for (int e = 0; e < 4; ++e) acc[i][j][e] = 0.0f;

    for (int chunk = 0; chunk < 3; ++chunk) {
        // ---- stage A (128 rows x 64 k floats = 8192 = 8 x 256thr x 4) ----
        const float* sp = (chunk == 0) ? uY : X;
        const int stride = (chunk == 0) ? 64 : 128;
        const int coloff = (chunk == 0) ? 0 : (chunk - 1) * 64;
        for (int it = 0; it < 8; ++it) {
            int flat = (it * 256 + t) * 4;      // float index within 128x64 tile
            int r = flat >> 6, k = flat & 63;
            int node = nb + r;
            float4 v = make_float4(0.f, 0.f, 0.f, 0.f);
            if (node < N) v = *(const float4*)(sp + (size_t)node * stride + coloff + k);
            unsigned short h0 = f2bf(v.x), h1 = f2bf(v.y), h2 = f2bf(v.z), h3 = f2bf(v.w);
            unsigned short l0 = f2bf(v.x - bf2f(h0)), l1 = f2bf(v.y - bf2f(h1));
            unsigned short l2 = f2bf(v.z - bf2f(h2)), l3 = f2bf(v.w - bf2f(h3));
            int boff = (r * 128 + k * 2) ^ ((r & 7) << 4);
            *(uint2*)((char*)Ah + boff) =
                make_uint2((unsigned)h0 | ((unsigned)h1 << 16), (unsigned)h2 | ((unsigned)h3 << 16));
            *(uint2*)((char*)Al + boff) =
                make_uint2((unsigned)l0 | ((unsigned)l1 << 16), (unsigned)l2 | ((unsigned)l3 << 16));
        }
        // ---- stage B (128 cols x 64 k from W1t hi/lo) ----
#pragma unroll
        for (int it = 0; it < 4; ++it) {
            int idx = it * 256 + t;             // 0..1023 granules of 8 bf16
            int c = idx >> 3, kb = (idx & 7) * 8;
            int goff = c * 192 + chunk * 64 + kb;
            uint4 hv = *(const uint4*)(Whi + goff);
            uint4 lv = *(const uint4*)(Wlo + goff);
            int boff = (c * 128 + kb * 2) ^ ((c & 7) << 4);
            *(uint4*)((char*)Bh + boff) = hv;
            *(uint4*)((char*)Bl + boff) = lv;
        }
        __syncthreads();

        // ---- compute: 2 k-steps of 32 ----
#pragma unroll
        for (int ks = 0; ks < 2; ++ks) {
            short8v afh[2], afl[2];
#pragma unroll
            for (int mf = 0; mf < 2; ++mf) {
                int r = wave * 32 + mf * 16 + lr;
                int k = ks * 32 + lg * 8;
                int boff = (r * 128 + k * 2) ^ ((r & 7) << 4);
                afh[mf] = *(short8v*)((char*)Ah + boff);
                afl[mf] = *(short8v*)((char*)Al + boff);
            }
#pragma unroll
            for (int nf = 0; nf < 8; ++nf) {
                int c = nf * 16 + lr;
                int k = ks * 32 + lg * 8;
                int boff = (c * 128 + k * 2) ^ ((c & 7) << 4);
                short8v bh = *(short8v*)((char*)Bh + boff);
                short8v bl = *(short8v*)((char*)Bl + boff);
#pragma unroll
                for (int mf = 0; mf < 2; ++mf) {
                    acc[mf][nf] = __builtin_amdgcn_mfma_f32_16x16x32_bf16(afh[mf], bh, acc[mf][nf], 0, 0, 0);
                    acc[mf][nf] = __builtin_amdgcn_mfma_f32_16x16x32_bf16(afh[mf], bl, acc[mf][nf], 0, 0, 0);
                    acc[mf][nf] = __builtin_amdgcn_mfma_f32_16x16x32_bf16(afl[mf], bh, acc[mf][nf], 0, 0, 0);
                }
            }
        }
        __syncthreads();
    }

    // ---- epilogue: scale by dinv, cast bf16, store ----
    // C/D layout (m89): col = lane&15, row = (lane>>4)*4 + reg
#pragma unroll
    for (int mf = 0; mf < 2; ++mf) {
#pragma unroll
        for (int r2 = 0; r2 < 4; ++r2) {
            int row = wave * 32 + mf * 16 + lg * 4 + r2;
            int node = nb + row;
            if (node >= N) continue;
            float dv = dvs[row];
#pragma unroll
            for (int nf = 0; nf < 8; ++nf) {
                int col = nf * 16 + lr;
                h1s[(size_t)node * 128 + col] = f2bf(acc[mf][nf][r2] * dv);
            }
        }
    }
}

// ---------------------------------------------------------------------------
// aggregate1 by gather (bf16 rows): one wave per node, lane = 2 channels
// out1[d] = bf16( dinv[d] * (h1s[d] + sum_nbr h1s[src]) ) ; 4 edges/iter
// ---------------------------------------------------------------------------
__global__ __launch_bounds__(256) void agg1_gather_k(
    const int* __restrict__ csr, const int* __restrict__ offs,
    const int* __restrict__ cnt, const float* __restrict__ dinv,
    const unsigned int* __restrict__ h1s, unsigned int* __restrict__ out1, int N) {
    int node = blockIdx.x * 4 + (threadIdx.x >> 6);
    if (node >= N) return;
    int lane = threadIdx.x & 63;
    int beg = offs[node], num = cnt[node];
    unsigned int w = h1s[(size_t)node * 64 + lane];
    float ax = bf2f(w & 0xFFFFu), ay = bf2f(w >> 16);
    int i = 0;
    for (; i + 3 < num; i += 4) {
        int s0 = csr[beg + i];
        int s1 = csr[beg + i + 1];
        int s2 = csr[beg + i + 2];
        int s3 = csr[beg + i + 3];
        unsigned int w0 = h1s[(size_t)s0 * 64 + lane];
        unsigned int w1 = h1s[(size_t)s1 * 64 + lane];
        unsigned int w2 = h1s[(size_t)s2 * 64 + lane];
        unsigned int w3 = h1s[(size_t)s3 * 64 + lane];
        ax += (bf2f(w0 & 0xFFFFu) + bf2f(w1 & 0xFFFFu)) +
              (bf2f(w2 & 0xFFFFu) + bf2f(w3 & 0xFFFFu));
        ay += (bf2f(w0 >> 16) + bf2f(w1 >> 16)) +
              (bf2f(w2 >> 16) + bf2f(w3 >> 16));
    }
    for (; i < num; ++i) {
        unsigned int w0 = h1s[(size_t)csr[beg + i] * 64 + lane];
        ax += bf2f(w0 & 0xFFFFu);
        ay += bf2f(w0 >> 16);
    }
    float dd = dinv[node];
    out1[(size_t)node * 64 + lane] = pack2bf(ax * dd, ay * dd);
}

// ---------------------------------------------------------------------------
// BN1 stats over bf16 out1: per-channel sum & sumsq
// ---------------------------------------------------------------------------
__global__ __launch_bounds__(256) void bn1_stats_k(const unsigned int* __restrict__ out1,
                                                   float* __restrict__ stats, int N) {
    __shared__ float4 ssum[256];
    __shared__ float4 ssq[256];
    int t = threadIdx.x;
    int c4 = t & 31, r = t >> 5;
    float4 sum = make_float4(0.f, 0.f, 0.f, 0.f);
    float4 sq  = make_float4(0.f, 0.f, 0.f, 0.f);
    for (int n = blockIdx.x * 8 + r; n < N; n += gridDim.x * 8) {
        uint2 w = *(const uint2*)(out1 + (size_t)n * 64 + c4 * 2);
        float v0 = bf2f(w.x & 0xFFFFu), v1 = bf2f(w.x >> 16);
        float v2 = bf2f(w.y & 0xFFFFu), v3 = bf2f(w.y >> 16);
        sum.x += v0; sum.y += v1; sum.z += v2; sum.w += v3;
        sq.x += v0 * v0; sq.y += v1 * v1; sq.z += v2 * v2; sq.w += v3 * v3;
    }
    ssum[t] = sum; ssq[t] = sq;
    __syncthreads();
    for (int sft = 128; sft >= 32; sft >>= 1) {
        if (t < sft) {
            ssum[t].x += ssum[t + sft].x; ssum[t].y += ssum[t + sft].y;
            ssum[t].z += ssum[t + sft].z; ssum[t].w += ssum[t + sft].w;
            ssq[t].x  += ssq[t + sft].x;  ssq[t].y  += ssq[t + sft].y;
            ssq[t].z  += ssq[t + sft].z;  ssq[t].w  += ssq[t + sft].w;
        }
        __syncthreads();
    }
    if (t < 32) {
        float4 a = ssum[t], b = ssq[t];
        atomicAdd(&stats[t * 4 + 0], a.x); atomicAdd(&stats[t * 4 + 1], a.y);
        atomicAdd(&stats[t * 4 + 2], a.z); atomicAdd(&stats[t * 4 + 3], a.w);
        atomicAdd(&stats[128 + t * 4 + 0], b.x); atomicAdd(&stats[128 + t * 4 + 1], b.y);
        atomicAdd(&stats[128 + t * 4 + 2], b.z); atomicAdd(&stats[128 + t * 4 + 3], b.w);
    }
}

__global__ void bn1_final_k(const float* __restrict__ stats,
                            const float* __restrict__ gamma1,
                            const float* __restrict__ beta1,
                            float* __restrict__ bn1, float invN) {
    int c = threadIdx.x;
    float mean = stats[c] * invN;
    float var  = stats[128 + c] * invN - mean * mean;
    float a = gamma1[c] * rsqrtf(var + BN_EPS);
    bn1[c] = a;
    bn1[128 + c] = beta1[c] - mean * a;
}

// ---------------------------------------------------------------------------
// GEMM2 fused: y = relu(BN1(out1)); h2s = (y @ W2) * dinv ; wave per node
// lane handles channel pair (2*lane, 2*lane+1)
// ---------------------------------------------------------------------------
__global__ __launch_bounds__(256) void gemm2_k(
    const unsigned int* __restrict__ out1, const float* __restrict__ bn1,
    const float* __restrict__ W2, const float* __restrict__ dinv,
    float* __restrict__ h2s, int N) {
    int node = blockIdx.x * 4 + (threadIdx.x >> 6);
    if (node >= N) return;
    int lane = threadIdx.x & 63;
    unsigned int w = out1[(size_t)node * 64 + lane];
    int c0 = lane * 2, c1 = lane * 2 + 1;
    float v0 = bf2f(w & 0xFFFFu), v1 = bf2f(w >> 16);
    float y0 = fmaxf(fmaf(bn1[c0], v0, bn1[128 + c0]), 0.f);
    float y1 = fmaxf(fmaf(bn1[c1], v1, bn1[128 + c1]), 0.f);
    float4 w2 = *(const float4*)(W2 + c0 * 2);   // rows c0,c1 of [128][2]
    float acc0 = y0 * w2.x + y1 * w2.z;
    float acc1 = y0 * w2.y + y1 * w2.w;
    for (int off = 32; off; off >>= 1) {
        acc0 += __shfl_xor(acc0, off);
        acc1 += __shfl_xor(acc1, off);
    }
    if (lane == 0) {
        float dv = dinv[node];
        *(float2*)(h2s + (size_t)node * 2) = make_float2(acc0 * dv, acc1 * dv);
    }
}

// aggregate2 by gather: one thread per node, both channels
__global__ __launch_bounds__(256) void agg2_gather_k(
    const int* __restrict__ csr, const int* __restrict__ offs,
    const int* __restrict__ cnt, const float* __restrict__ dinv,
    const float* __restrict__ h2s, float* __restrict__ out2, int N) {
    int node = blockIdx.x * 256 + threadIdx.x;
    if (node >= N) return;
    int beg = offs[node], num = cnt[node];
    float2 acc = *(const float2*)(h2s + (size_t)node * 2);
    for (int i = 0; i < num; ++i) {
        int s = csr[beg + i];
        float2 v = *(const float2*)(h2s + (size_t)s * 2);
        acc.x += v.x;
        acc.y += v.y;
    }
    float dd = dinv[node];
    *(float2*)(out2 + (size_t)node * 2) = make_float2(acc.x * dd, acc.y * dd);
}

// BN2 stats
__global__ __launch_bounds__(256) void bn2_stats_k(const float* __restrict__ out2,
                                                   float* __restrict__ stats, int N) {
    __shared__ float4 red[256];
    int t = threadIdx.x;
    float4 acc = make_float4(0.f, 0.f, 0.f, 0.f);
    for (int n = blockIdx.x * 256 + t; n < N; n += gridDim.x * 256) {
        float2 v = *(const float2*)(out2 + (size_t)n * 2);
        acc.x += v.x; acc.y += v.y; acc.z += v.x * v.x; acc.w += v.y * v.y;
    }
    red[t] = acc;
    __syncthreads();
    for (int s = 128; s; s >>= 1) {
        if (t < s) {
            red[t].x += red[t + s].x; red[t].y += red[t + s].y;
            red[t].z += red[t + s].z; red[t].w += red[t + s].w;
        }
        __syncthreads();
    }
    if (t == 0) {
        atomicAdd(&stats[0], red[0].x); atomicAdd(&stats[1], red[0].y);
        atomicAdd(&stats[2], red[0].z); atomicAdd(&stats[3], red[0].w);
    }
}

// final: BN2 + softmax(2)
__global__ __launch_bounds__(256) void final_k(
    const float* __restrict__ out2, const float* __restrict__ stats,
    const float* __restrict__ gamma2, const float* __restrict__ beta2,
    float* __restrict__ outp, int N, float invN) {
    int i = blockIdx.x * 256 + threadIdx.x;
    if (i >= N) return;
    float m0 = stats[0] * invN, m1 = stats[1] * invN;
    float var0 = stats[2] * invN - m0 * m0;
    float var1 = stats[3] * invN - m1 * m1;
    float a0 = gamma2[0] * rsqrtf(var0 + BN_EPS);
    float a1 = gamma2[1] * rsqrtf(var1 + BN_EPS);
    float c0 = beta2[0] - m0 * a0;
    float c1 = beta2[1] - m1 * a1;
    float2 v = *(const float2*)(out2 + (size_t)i * 2);
    float y0 = fmaf(a0, v.x, c0);
    float y1 = fmaf(a1, v.y, c1);
    float mx = fmaxf(y0, y1);
    float e0 = expf(y0 - mx), e1 = expf(y1 - mx);
    float inv = 1.f / (e0 + e1);
    *(float2*)(outp + (size_t)i * 2) = make_float2(e0 * inv, e1 * inv);
}

// ---------------------------------------------------------------------------
extern "C" void kernel_launch(void* const* d_in, const int* in_sizes, int n_in,
                              void* d_out, int out_size, void* d_ws, size_t ws_size,
                              hipStream_t stream) {
    const int*   edge   = (const int*)d_in[0];
    const float* X      = (const float*)d_in[1];
    const float* uY     = (const float*)d_in[2];
    const float* W1     = (const float*)d_in[3];
    // b1/b2 cancel under BatchNorm -- skipped
    const float* W2     = (const float*)d_in[5];
    const float* gamma1 = (const float*)d_in[7];
    const float* beta1  = (const float*)d_in[8];
    const float* gamma2 = (const float*)d_in[9];
    const float* beta2  = (const float*)d_in[10];

    const int E = in_sizes[0] / 2;
    const int N = in_sizes[1] / 128;
    const int* srcI = edge;
    const int* dstI = edge + E;

    // workspace layout (4-byte words); fixed small arrays first for alignment:
    // stats1[256] bn1[256] stats2[64] Whi[12288] Wlo[12288] blksum[256]
    // h1s[N*64] out1[N*64] dinv[N] h2s[2N] out2[2N] cnt[N] offs[N] cur[N] csr[E]
    float* stats1 = (float*)d_ws;
    float* bn1    = stats1 + 256;
    float* stats2 = bn1 + 256;
    unsigned short* Whi = (unsigned short*)(stats2 + 64);     // 128*192 bf16
    unsigned short* Wlo = Whi + 128 * 192;
    int*   blksum = (int*)(Wlo + 128 * 192);
    unsigned int* h1s  = (unsigned int*)(blksum + 256);       // N*128 bf16
    unsigned int* out1 = h1s + (size_t)N * 64;                // N*128 bf16
    float* dinv   = (float*)(out1 + (size_t)N * 64);
    float* h2s    = dinv + N;
    float* out2   = h2s + (size_t)N * 2;
    int*   cnt    = (int*)(out2 + (size_t)N * 2);
    int*   offs   = cnt + N;
    int*   cur    = offs + N;
    int*   csr    = cur + N;

    hipMemsetAsync(cnt,    0, (size_t)N * sizeof(int), stream);
    hipMemsetAsync(cur,    0, (size_t)N * sizeof(int), stream);
    hipMemsetAsync(stats1, 0, 256 * sizeof(float), stream);
    hipMemsetAsync(stats2, 0, 4 * sizeof(float), stream);

    const int NB = (N + 1023) / 1024;

    deg_count_k<<<(E / 4 + 255) / 256, 256, 0, stream>>>(dstI, cnt, E);
    scan_a_k<<<NB, 256, 0, stream>>>(cnt, offs, blksum, dinv, N);
    scan_b_k<<<1, 256, 0, stream>>>(blksum, NB);
    scan_c_k<<<NB * 4, 256, 0, stream>>>(offs, blksum, N);
    scatter_k<<<(E / 4 + 255) / 256, 256, 0, stream>>>(srcI, dstI, offs, cur, csr, E);

    w1cast_k<<<(192 * 128 + 255) / 256, 256, 0, stream>>>(W1, Whi, Wlo);
    gemm1_mfma_k<<<(N + 127) / 128, 256, 0, stream>>>(uY, X, Whi, Wlo, dinv,
                                                      (unsigned short*)h1s, N);
    agg1_gather_k<<<(N + 3) / 4, 256, 0, stream>>>(csr, offs, cnt, dinv, h1s, out1, N);
    bn1_stats_k<<<512, 256, 0, stream>>>(out1, stats1, N);
    bn1_final_k<<<1, 128, 0, stream>>>(stats1, gamma1, beta1, bn1, 1.0f / N);
    gemm2_k<<<(N + 3) / 4, 256, 0, stream>>>(out1, bn1, W2, dinv, h2s, N);
    agg2_gather_k<<<(N + 255) / 256, 256, 0, stream>>>(csr, offs, cnt, dinv, h2s, out2, N);
    bn2_stats_k<<<256, 256, 0, stream>>>(out2, stats2, N);
    final_k<<<(N + 255) / 256, 256, 0, stream>>>(out2, stats2, gamma2, beta2,
                                                 (float*)d_out, N, 1.0f / N);
}

// Round 10
// 453.329 us; speedup vs baseline: 4.0520x; 1.1451x over previous
//
#include <hip/hip_runtime.h>
#include <math.h>

#define BN_EPS 1e-5f
#define CHUNK 16384          // edges per partition chunk
#define BSHIFT 8             // 256 nodes per bucket
#define BCAP 6144            // max edges per bucket (avg 4096, Poisson; huge slack)

typedef __attribute__((ext_vector_type(8))) short short8v;
typedef __attribute__((ext_vector_type(4))) float f32x4;

__device__ __forceinline__ unsigned short f2bf(float x) {
    unsigned int u = __float_as_uint(x);
    u += 0x7FFFu + ((u >> 16) & 1u);     // RNE
    return (unsigned short)(u >> 16);
}
__device__ __forceinline__ float bf2f(unsigned int u16) {
    return __uint_as_float(u16 << 16);
}
__device__ __forceinline__ unsigned int pack2bf(float a, float b) {
    return (unsigned int)f2bf(a) | ((unsigned int)f2bf(b) << 16);
}

// ---------------------------------------------------------------------------
// K1: per-chunk histogram over dst buckets (dst>>8).  histT[b*nchunk + c]
// ---------------------------------------------------------------------------
__global__ __launch_bounds__(256) void hist_k(const int* __restrict__ dst,
                                              int* __restrict__ histT,
                                              int E, int nchunk, int nbucket) {
    __shared__ int hcnt[512];
    const int c = blockIdx.x, t = threadIdx.x;
    for (int b = t; b < nbucket; b += 256) hcnt[b] = 0;
    __syncthreads();
    const int base = c * CHUNK;
    for (int i = t * 4; i < CHUNK; i += 1024) {
        int e = base + i;
        if (e + 3 < E) {
            int4 d = *(const int4*)(dst + e);
            atomicAdd(&hcnt[d.x >> BSHIFT], 1);
            atomicAdd(&hcnt[d.y >> BSHIFT], 1);
            atomicAdd(&hcnt[d.z >> BSHIFT], 1);
            atomicAdd(&hcnt[d.w >> BSHIFT], 1);
        } else {
            for (int j = e; j < E; ++j) atomicAdd(&hcnt[dst[j] >> BSHIFT], 1);
        }
    }
    __syncthreads();
    for (int b = t; b < nbucket; b += 256) histT[b * nchunk + c] = hcnt[b];
}

// ---------------------------------------------------------------------------
// K2: single-block exclusive scan over histT (bucket-major, total entries)
//     plus sentinel histT[total] = E
// ---------------------------------------------------------------------------
__global__ __launch_bounds__(256) void scanhist_k(int* __restrict__ h,
                                                  int total, int E) {
    __shared__ int s[256];
    __shared__ int carry;
    int t = threadIdx.x;
    if (t == 0) carry = 0;
    __syncthreads();
    int iters = (total + 1023) >> 10;
    for (int it = 0; it < iters; ++it) {
        int c0 = carry;
        int base = it * 1024 + t * 4;
        int v0 = 0, v1 = 0, v2 = 0, v3 = 0;
        if (base + 3 < total) {
            int4 q = *(const int4*)(h + base);
            v0 = q.x; v1 = q.y; v2 = q.z; v3 = q.w;
        } else {
            if (base     < total) v0 = h[base];
            if (base + 1 < total) v1 = h[base + 1];
            if (base + 2 < total) v2 = h[base + 2];
            if (base + 3 < total) v3 = h[base + 3];
        }
        int ts = v0 + v1 + v2 + v3;
        s[t] = ts;
        __syncthreads();
        for (int o = 1; o < 256; o <<= 1) {
            int x = (t >= o) ? s[t - o] : 0;
            __syncthreads();
            s[t] += x;
            __syncthreads();
        }
        int excl = s[t] - ts + c0;
        int e0 = excl, e1 = e0 + v0, e2 = e1 + v1, e3 = e2 + v2;
        if (base     < total) h[base]     = e0;
        if (base + 1 < total) h[base + 1] = e1;
        if (base + 2 < total) h[base + 2] = e2;
        if (base + 3 < total) h[base + 3] = e3;
        __syncthreads();
        if (t == 0) carry = c0 + s[255];
        __syncthreads();
    }
    if (t == 0) h[total] = E;
}

// ---------------------------------------------------------------------------
// K3: partition edges into bucket-grouped runs (coalesced-ish block-private
//     writes). pack = src | (dst&255)<<20
// ---------------------------------------------------------------------------
__global__ __launch_bounds__(256) void partition_k(
    const int* __restrict__ src, const int* __restrict__ dst,
    const int* __restrict__ scanned, unsigned int* __restrict__ pack,
    int E, int nchunk, int nbucket) {
    __shared__ int basebc[512];
    __shared__ int cur[512];
    const int c = blockIdx.x, t = threadIdx.x;
    for (int b = t; b < nbucket; b += 256) {
        basebc[b] = scanned[b * nchunk + c];
        cur[b] = 0;
    }
    __syncthreads();
    const int base = c * CHUNK;
    for (int i = t * 4; i < CHUNK; i += 1024) {
        int e = base + i;
        if (e + 3 < E) {
            int4 sv = *(const int4*)(src + e);
            int4 dv = *(const int4*)(dst + e);
            int b0 = dv.x >> BSHIFT, b1 = dv.y >> BSHIFT;
            int b2 = dv.z >> BSHIFT, b3 = dv.w >> BSHIFT;
            int p0 = basebc[b0] + atomicAdd(&cur[b0], 1);
            int p1 = basebc[b1] + atomicAdd(&cur[b1], 1);
            int p2 = basebc[b2] + atomicAdd(&cur[b2], 1);
            int p3 = basebc[b3] + atomicAdd(&cur[b3], 1);
            pack[p0] = (unsigned)sv.x | ((unsigned)(dv.x & 255) << 20);
            pack[p1] = (unsigned)sv.y | ((unsigned)(dv.y & 255) << 20);
            pack[p2] = (unsigned)sv.z | ((unsigned)(dv.z & 255) << 20);
            pack[p3] = (unsigned)sv.w | ((unsigned)(dv.w & 255) << 20);
        } else {
            for (int j = e; j < E; ++j) {
                int d = dst[j];
                int b = d >> BSHIFT;
                int p = basebc[b] + atomicAdd(&cur[b], 1);
                pack[p] = (unsigned)src[j] | ((unsigned)(d & 255) << 20);
            }
        }
    }
}

// ---------------------------------------------------------------------------
// K4: per-bucket LDS counting sort by dst&255 -> dst-sorted CSR (coalesced
//     write) + per-node cnt/offs/dinv
// ---------------------------------------------------------------------------
__global__ __launch_bounds__(256) void bucket_k(
    const unsigned int* __restrict__ pack, const int* __restrict__ scanned,
    int* __restrict__ csr, int* __restrict__ offs_g, int* __restrict__ cnt_g,
    float* __restrict__ dinv, int N, int nchunk) {
    __shared__ unsigned int arr[BCAP];
    __shared__ unsigned int csr_l[BCAP];
    __shared__ int cnt[256], off[256], cur[256], sscan[256];
    const int b = blockIdx.x, t = threadIdx.x;
    const int base = scanned[b * nchunk];
    int cb = scanned[(b + 1) * nchunk] - base;
    if (cb > BCAP) cb = BCAP;   // never happens for this input
    for (int i = t; i < cb; i += 256) arr[i] = pack[base + i];
    cnt[t] = 0; cur[t] = 0;
    __syncthreads();
    for (int i = t; i < cb; i += 256) atomicAdd(&cnt[arr[i] >> 20], 1);
    __syncthreads();
    int v = cnt[t];
    sscan[t] = v;
    __syncthreads();
    for (int o = 1; o < 256; o <<= 1) {
        int x = (t >= o) ? sscan[t - o] : 0;
        __syncthreads();
        sscan[t] += x;
        __syncthreads();
    }
    off[t] = sscan[t] - v;
    __syncthreads();
    for (int i = t; i < cb; i += 256) {
        unsigned int a = arr[i];
        int dl = a >> 20;
        int p = off[dl] + atomicAdd(&cur[dl], 1);
        csr_l[p] = a & 0xFFFFFu;
    }
    __syncthreads();
    for (int i = t; i < cb; i += 256) csr[base + i] = (int)csr_l[i];
    int node = (b << BSHIFT) + t;
    if (node < N) {
        cnt_g[node]  = cnt[t];
        offs_g[node] = base + off[t];
        dinv[node]   = rsqrtf((float)cnt[t] + 1.0f);
    }
}

// ---------------------------------------------------------------------------
// W1 cast: [192][128] f32 -> transposed hi/lo bf16 [128 cols][192 k]
// ---------------------------------------------------------------------------
__global__ __launch_bounds__(256) void w1cast_k(const float* __restrict__ W1,
                                                unsigned short* __restrict__ Whi,
                                                unsigned short* __restrict__ Wlo) {
    int t = blockIdx.x * 256 + threadIdx.x;   // 0 .. 192*128-1
    if (t >= 192 * 128) return;
    int k = t >> 7, c = t & 127;
    float v = W1[t];
    unsigned short hi = f2bf(v);
    float lo = v - bf2f(hi);
    Whi[c * 192 + k] = hi;
    Wlo[c * 192 + k] = f2bf(lo);
}

// ---------------------------------------------------------------------------
// GEMM1 (MFMA, split-bf16): h1s = ([uY | X] @ W1) * dinv[node],  bf16 out
// ---------------------------------------------------------------------------
__global__ __launch_bounds__(256) void gemm1_mfma_k(
    const float* __restrict__ uY, const float* __restrict__ X,
    const unsigned short* __restrict__ Whi, const unsigned short* __restrict__ Wlo,
    const float* __restrict__ dinv, unsigned short* __restrict__ h1s, int N) {
    __shared__ unsigned short Ah[128 * 64];
    __shared__ unsigned short Al[128 * 64];
    __shared__ unsigned short Bh[128 * 64];
    __shared__ unsigned short Bl[128 * 64];
    __shared__ float dvs[128];
    const int t = threadIdx.x;
    const int wave = t >> 6, lane = t & 63;
    const int lr = lane & 15, lg = lane >> 4;
    const int nb = blockIdx.x * 128;

    if (t < 128) {
        int node = nb + t;
        dvs[t] = (node < N) ? dinv[node] : 0.0f;
    }

    f32x4 acc[2][8];
    for (int i = 0; i < 2; ++i)
        for (int j = 0; j < 8; ++j)
            for (int e = 0; e < 4; ++e) acc[i][j][e] = 0.0f;

    for (int chunk = 0; chunk < 3; ++chunk) {
        const float* sp = (chunk == 0) ? uY : X;
        const int stride = (chunk == 0) ? 64 : 128;
        const int coloff = (chunk == 0) ? 0 : (chunk - 1) * 64;
        for (int it = 0; it < 8; ++it) {
            int flat = (it * 256 + t) * 4;
            int r = flat >> 6, k = flat & 63;
            int node = nb + r;
            float4 v = make_float4(0.f, 0.f, 0.f, 0.f);
            if (node < N) v = *(const float4*)(sp + (size_t)node * stride + coloff + k);
            unsigned short h0 = f2bf(v.x), h1 = f2bf(v.y), h2 = f2bf(v.z), h3 = f2bf(v.w);
            unsigned short l0 = f2bf(v.x - bf2f(h0)), l1 = f2bf(v.y - bf2f(h1));
            unsigned short l2 = f2bf(v.z - bf2f(h2)), l3 = f2bf(v.w - bf2f(h3));
            int boff = (r * 128 + k * 2) ^ ((r & 7) << 4);
            *(uint2*)((char*)Ah + boff) =
                make_uint2((unsigned)h0 | ((unsigned)h1 << 16), (unsigned)h2 | ((unsigned)h3 << 16));
            *(uint2*)((char*)Al + boff) =
                make_uint2((unsigned)l0 | ((unsigned)l1 << 16), (unsigned)l2 | ((unsigned)l3 << 16));
        }
#pragma unroll
        for (int it = 0; it < 4; ++it) {
            int idx = it * 256 + t;
            int c = idx >> 3, kb = (idx & 7) * 8;
            int goff = c * 192 + chunk * 64 + kb;
            uint4 hv = *(const uint4*)(Whi + goff);
            uint4 lv = *(const uint4*)(Wlo + goff);
            int boff = (c * 128 + kb * 2) ^ ((c & 7) << 4);
            *(uint4*)((char*)Bh + boff) = hv;
            *(uint4*)((char*)Bl + boff) = lv;
        }
        __syncthreads();

#pragma unroll
        for (int ks = 0; ks < 2; ++ks) {
            short8v afh[2], afl[2];
#pragma unroll
            for (int mf = 0; mf < 2; ++mf) {
                int r = wave * 32 + mf * 16 + lr;
                int k = ks * 32 + lg * 8;
                int boff = (r * 128 + k * 2) ^ ((r & 7) << 4);
                afh[mf] = *(short8v*)((char*)Ah + boff);
                afl[mf] = *(short8v*)((char*)Al + boff);
            }
#pragma unroll
            for (int nf = 0; nf < 8; ++nf) {
                int c = nf * 16 + lr;
                int k = ks * 32 + lg * 8;
                int boff = (c * 128 + k * 2) ^ ((c & 7) << 4);
                short8v bh = *(short8v*)((char*)Bh + boff);
                short8v bl = *(short8v*)((char*)Bl + boff);
#pragma unroll
                for (int mf = 0; mf < 2; ++mf) {
                    acc[mf][nf] = __builtin_amdgcn_mfma_f32_16x16x32_bf16(afh[mf], bh, acc[mf][nf], 0, 0, 0);
                    acc[mf][nf] = __builtin_amdgcn_mfma_f32_16x16x32_bf16(afh[mf], bl, acc[mf][nf], 0, 0, 0);
                    acc[mf][nf] = __builtin_amdgcn_mfma_f32_16x16x32_bf16(afl[mf], bh, acc[mf][nf], 0, 0, 0);
                }
            }
        }
        __syncthreads();
    }

    // C/D layout (m89): col = lane&15, row = (lane>>4)*4 + reg
#pragma unroll
    for (int mf = 0; mf < 2; ++mf) {
#pragma unroll
        for (int r2 = 0; r2 < 4; ++r2) {
            int row = wave * 32 + mf * 16 + lg * 4 + r2;
            int node = nb + row;
            if (node >= N) continue;
            float dv = dvs[row];
#pragma unroll
            for (int nf = 0; nf < 8; ++nf) {
                int col = nf * 16 + lr;
                h1s[(size_t)node * 128 + col] = f2bf(acc[mf][nf][r2] * dv);
            }
        }
    }
}

// ---------------------------------------------------------------------------
// aggregate1 by gather (bf16 rows): one wave per node, lane = 2 channels
// ---------------------------------------------------------------------------
__global__ __launch_bounds__(256) void agg1_gather_k(
    const int* __restrict__ csr, const int* __restrict__ offs,
    const int* __restrict__ cnt, const float* __restrict__ dinv,
    const unsigned int* __restrict__ h1s, unsigned int* __restrict__ out1, int N) {
    int node = blockIdx.x * 4 + (threadIdx.x >> 6);
    if (node >= N) return;
    int lane = threadIdx.x & 63;
    int beg = offs[node], num = cnt[node];
    unsigned int w = h1s[(size_t)node * 64 + lane];
    float ax = bf2f(w & 0xFFFFu), ay = bf2f(w >> 16);
    int i = 0;
    for (; i + 3 < num; i += 4) {
        int s0 = csr[beg + i];
        int s1 = csr[beg + i + 1];
        int s2 = csr[beg + i + 2];
        int s3 = csr[beg + i + 3];
        unsigned int w0 = h1s[(size_t)s0 * 64 + lane];
        unsigned int w1 = h1s[(size_t)s1 * 64 + lane];
        unsigned int w2 = h1s[(size_t)s2 * 64 + lane];
        unsigned int w3 = h1s[(size_t)s3 * 64 + lane];
        ax += (bf2f(w0 & 0xFFFFu) + bf2f(w1 & 0xFFFFu)) +
              (bf2f(w2 & 0xFFFFu) + bf2f(w3 & 0xFFFFu));
        ay += (bf2f(w0 >> 16) + bf2f(w1 >> 16)) +
              (bf2f(w2 >> 16) + bf2f(w3 >> 16));
    }
    for (; i < num; ++i) {
        unsigned int w0 = h1s[(size_t)csr[beg + i] * 64 + lane];
        ax += bf2f(w0 & 0xFFFFu);
        ay += bf2f(w0 >> 16);
    }
    float dd = dinv[node];
    out1[(size_t)node * 64 + lane] = pack2bf(ax * dd, ay * dd);
}

// ---------------------------------------------------------------------------
// BN1 stats over bf16 out1: per-channel sum & sumsq
// ---------------------------------------------------------------------------
__global__ __launch_bounds__(256) void bn1_stats_k(const unsigned int* __restrict__ out1,
                                                   float* __restrict__ stats, int N) {
    __shared__ float4 ssum[256];
    __shared__ float4 ssq[256];
    int t = threadIdx.x;
    int c4 = t & 31, r = t >> 5;
    float4 sum = make_float4(0.f, 0.f, 0.f, 0.f);
    float4 sq  = make_float4(0.f, 0.f, 0.f, 0.f);
    for (int n = blockIdx.x * 8 + r; n < N; n += gridDim.x * 8) {
        uint2 w = *(const uint2*)(out1 + (size_t)n * 64 + c4 * 2);
        float v0 = bf2f(w.x & 0xFFFFu), v1 = bf2f(w.x >> 16);
        float v2 = bf2f(w.y & 0xFFFFu), v3 = bf2f(w.y >> 16);
        sum.x += v0; sum.y += v1; sum.z += v2; sum.w += v3;
        sq.x += v0 * v0; sq.y += v1 * v1; sq.z += v2 * v2; sq.w += v3 * v3;
    }
    ssum[t] = sum; ssq[t] = sq;
    __syncthreads();
    for (int sft = 128; sft >= 32; sft >>= 1) {
        if (t < sft) {
            ssum[t].x += ssum[t + sft].x; ssum[t].y += ssum[t + sft].y;
            ssum[t].z += ssum[t + sft].z; ssum[t].w += ssum[t + sft].w;
            ssq[t].x  += ssq[t + sft].x;  ssq[t].y  += ssq[t + sft].y;
            ssq[t].z  += ssq[t + sft].z;  ssq[t].w  += ssq[t + sft].w;
        }
        __syncthreads();
    }
    if (t < 32) {
        float4 a = ssum[t], b = ssq[t];
        atomicAdd(&stats[t * 4 + 0], a.x); atomicAdd(&stats[t * 4 + 1], a.y);
        atomicAdd(&stats[t * 4 + 2], a.z); atomicAdd(&stats[t * 4 + 3], a.w);
        atomicAdd(&stats[128 + t * 4 + 0], b.x); atomicAdd(&stats[128 + t * 4 + 1], b.y);
        atomicAdd(&stats[128 + t * 4 + 2], b.z); atomicAdd(&stats[128 + t * 4 + 3], b.w);
    }
}

__global__ void bn1_final_k(const float* __restrict__ stats,
                            const float* __restrict__ gamma1,
                            const float* __restrict__ beta1,
                            float* __restrict__ bn1, float invN) {
    int c = threadIdx.x;
    float mean = stats[c] * invN;
    float var  = stats[128 + c] * invN - mean * mean;
    float a = gamma1[c] * rsqrtf(var + BN_EPS);
    bn1[c] = a;
    bn1[128 + c] = beta1[c] - mean * a;
}

// ---------------------------------------------------------------------------
// GEMM2 fused: y = relu(BN1(out1)); h2s = (y @ W2) * dinv ; wave per node
// ---------------------------------------------------------------------------
__global__ __launch_bounds__(256) void gemm2_k(
    const unsigned int* __restrict__ out1, const float* __restrict__ bn1,
    const float* __restrict__ W2, const float* __restrict__ dinv,
    float* __restrict__ h2s, int N) {
    int node = blockIdx.x * 4 + (threadIdx.x >> 6);
    if (node >= N) return;
    int lane = threadIdx.x & 63;
    unsigned int w = out1[(size_t)node * 64 + lane];
    int c0 = lane * 2, c1 = lane * 2 + 1;
    float v0 = bf2f(w & 0xFFFFu), v1 = bf2f(w >> 16);
    float y0 = fmaxf(fmaf(bn1[c0], v0, bn1[128 + c0]), 0.f);
    float y1 = fmaxf(fmaf(bn1[c1], v1, bn1[128 + c1]), 0.f);
    float4 w2 = *(const float4*)(W2 + c0 * 2);   // rows c0,c1 of [128][2]
    float acc0 = y0 * w2.x + y1 * w2.z;
    float acc1 = y0 * w2.y + y1 * w2.w;
    for (int off = 32; off; off >>= 1) {
        acc0 += __shfl_xor(acc0, off);
        acc1 += __shfl_xor(acc1, off);
    }
    if (lane == 0) {
        float dv = dinv[node];
        *(float2*)(h2s + (size_t)node * 2) = make_float2(acc0 * dv, acc1 * dv);
    }
}

// aggregate2 by gather: one thread per node, both channels
__global__ __launch_bounds__(256) void agg2_gather_k(
    const int* __restrict__ csr, const int* __restrict__ offs,
    const int* __restrict__ cnt, const float* __restrict__ dinv,
    const float* __restrict__ h2s, float* __restrict__ out2, int N) {
    int node = blockIdx.x * 256 + threadIdx.x;
    if (node >= N) return;
    int beg = offs[node], num = cnt[node];
    float2 acc = *(const float2*)(h2s + (size_t)node * 2);
    for (int i = 0; i < num; ++i) {
        int s = csr[beg + i];
        float2 v = *(const float2*)(h2s + (size_t)s * 2);
        acc.x += v.x;
        acc.y += v.y;
    }
    float dd = dinv[node];
    *(float2*)(out2 + (size_t)node * 2) = make_float2(acc.x * dd, acc.y * dd);
}

// BN2 stats
__global__ __launch_bounds__(256) void bn2_stats_k(const float* __restrict__ out2,
                                                   float* __restrict__ stats, int N) {
    __shared__ float4 red[256];
    int t = threadIdx.x;
    float4 acc = make_float4(0.f, 0.f, 0.f, 0.f);
    for (int n = blockIdx.x * 256 + t; n < N; n += gridDim.x * 256) {
        float2 v = *(const float2*)(out2 + (size_t)n * 2);
        acc.x += v.x; acc.y += v.y; acc.z += v.x * v.x; acc.w += v.y * v.y;
    }
    red[t] = acc;
    __syncthreads();
    for (int s = 128; s; s >>= 1) {
        if (t < s) {
            red[t].x += red[t + s].x; red[t].y += red[t + s].y;
            red[t].z += red[t + s].z; red[t].w += red[t + s].w;
        }
        __syncthreads();
    }
    if (t == 0) {
        atomicAdd(&stats[0], red[0].x); atomicAdd(&stats[1], red[0].y);
        atomicAdd(&stats[2], red[0].z); atomicAdd(&stats[3], red[0].w);
    }
}

// final: BN2 + softmax(2)
__global__ __launch_bounds__(256) void final_k(
    const float* __restrict__ out2, const float* __restrict__ stats,
    const float* __restrict__ gamma2, const float* __restrict__ beta2,
    float* __restrict__ outp, int N, float invN) {
    int i = blockIdx.x * 256 + threadIdx.x;
    if (i >= N) return;
    float m0 = stats[0] * invN, m1 = stats[1] * invN;
    float var0 = stats[2] * invN - m0 * m0;
    float var1 = stats[3] * invN - m1 * m1;
    float a0 = gamma2[0] * rsqrtf(var0 + BN_EPS);
    float a1 = gamma2[1] * rsqrtf(var1 + BN_EPS);
    float c0 = beta2[0] - m0 * a0;
    float c1 = beta2[1] - m1 * a1;
    float2 v = *(const float2*)(out2 + (size_t)i * 2);
    float y0 = fmaf(a0, v.x, c0);
    float y1 = fmaf(a1, v.y, c1);
    float mx = fmaxf(y0, y1);
    float e0 = expf(y0 - mx), e1 = expf(y1 - mx);
    float inv = 1.f / (e0 + e1);
    *(float2*)(outp + (size_t)i * 2) = make_float2(e0 * inv, e1 * inv);
}

// ---------------------------------------------------------------------------
extern "C" void kernel_launch(void* const* d_in, const int* in_sizes, int n_in,
                              void* d_out, int out_size, void* d_ws, size_t ws_size,
                              hipStream_t stream) {
    const int*   edge   = (const int*)d_in[0];
    const float* X      = (const float*)d_in[1];
    const float* uY     = (const float*)d_in[2];
    const float* W1     = (const float*)d_in[3];
    // b1/b2 cancel under BatchNorm -- skipped
    const float* W2     = (const float*)d_in[5];
    const float* gamma1 = (const float*)d_in[7];
    const float* beta1  = (const float*)d_in[8];
    const float* gamma2 = (const float*)d_in[9];
    const float* beta2  = (const float*)d_in[10];

    const int E = in_sizes[0] / 2;
    const int N = in_sizes[1] / 128;
    const int* srcI = edge;
    const int* dstI = edge + E;

    const int nchunk  = (E + CHUNK - 1) / CHUNK;
    const int nbucket = (N + 255) >> BSHIFT;
    const int total   = nbucket * nchunk;

    // workspace layout (4-byte words):
    // stats1[256] bn1[256] stats2[64] Whi[6144w] Wlo[6144w]
    // h1s[N*64] out1[N*64] dinv[N] h2s[2N] out2[2N] cnt[N] offs[N]
    // histT[total+1] pack[E] csr[E]
    float* stats1 = (float*)d_ws;
    float* bn1    = stats1 + 256;
    float* stats2 = bn1 + 256;
    unsigned short* Whi = (unsigned short*)(stats2 + 64);     // 128*192 bf16
    unsigned short* Wlo = Whi + 128 * 192;
    unsigned int* h1s  = (unsigned int*)(Wlo + 128 * 192);
    unsigned int* out1 = h1s + (size_t)N * 64;
    float* dinv   = (float*)(out1 + (size_t)N * 64);
    float* h2s    = dinv + N;
    float* out2   = h2s + (size_t)N * 2;
    int*   cnt    = (int*)(out2 + (size_t)N * 2);
    int*   offs   = cnt + N;
    int*   histT  = offs + N;
    unsigned int* pack = (unsigned int*)(histT + total + 1);
    int*   csr    = (int*)(pack + E);

    hipMemsetAsync(stats1, 0, 256 * sizeof(float), stream);
    hipMemsetAsync(stats2, 0, 4 * sizeof(float), stream);

    // CSR build: histogram -> scan -> partition -> per-bucket sort
    hist_k<<<nchunk, 256, 0, stream>>>(dstI, histT, E, nchunk, nbucket);
    scanhist_k<<<1, 256, 0, stream>>>(histT, total, E);
    partition_k<<<nchunk, 256, 0, stream>>>(srcI, dstI, histT, pack, E, nchunk, nbucket);
    bucket_k<<<nbucket, 256, 0, stream>>>(pack, histT, csr, offs, cnt, dinv, N, nchunk);

    w1cast_k<<<(192 * 128 + 255) / 256, 256, 0, stream>>>(W1, Whi, Wlo);
    gemm1_mfma_k<<<(N + 127) / 128, 256, 0, stream>>>(uY, X, Whi, Wlo, dinv,
                                                      (unsigned short*)h1s, N);
    agg1_gather_k<<<(N + 3) / 4, 256, 0, stream>>>(csr, offs, cnt, dinv, h1s, out1, N);
    bn1_stats_k<<<512, 256, 0, stream>>>(out1, stats1, N);
    bn1_final_k<<<1, 128, 0, stream>>>(stats1, gamma1, beta1, bn1, 1.0f / N);
    gemm2_k<<<(N + 3) / 4, 256, 0, stream>>>(out1, bn1, W2, dinv, h2s, N);
    agg2_gather_k<<<(N + 255) / 256, 256, 0, stream>>>(csr, offs, cnt, dinv, h2s, out2, N);
    bn2_stats_k<<<256, 256, 0, stream>>>(out2, stats2, N);
    final_k<<<(N + 255) / 256, 256, 0, stream>>>(out2, stats2, gamma2, beta2,
                                                 (float*)d_out, N, 1.0f / N);
}

// Round 13
// 390.163 us; speedup vs baseline: 4.7080x; 1.1619x over previous
//
#include <hip/hip_runtime.h>
#include <math.h>

#define BN_EPS 1e-5f
#define CHUNK 8192           // edges per partition chunk (196 chunks -> good CU coverage)
#define BSHIFT 8             // 256 nodes per bucket
#define BCAP 6144            // max edges per bucket (avg 4096; +32 sigma slack)

typedef __attribute__((ext_vector_type(8))) short short8v;
typedef __attribute__((ext_vector_type(4))) float f32x4;

__device__ __forceinline__ unsigned short f2bf(float x) {
    unsigned int u = __float_as_uint(x);
    u += 0x7FFFu + ((u >> 16) & 1u);     // RNE
    return (unsigned short)(u >> 16);
}
__device__ __forceinline__ float bf2f(unsigned int u16) {
    return __uint_as_float(u16 << 16);
}
__device__ __forceinline__ unsigned int pack2bf(float a, float b) {
    return (unsigned int)f2bf(a) | ((unsigned int)f2bf(b) << 16);
}

// ---------------------------------------------------------------------------
// K1: per-chunk histogram over dst buckets (dst>>8).  histT[b*nchunk + c]
// ---------------------------------------------------------------------------
__global__ __launch_bounds__(256) void hist_k(const int* __restrict__ dst,
                                              int* __restrict__ histT,
                                              int E, int nchunk, int nbucket) {
    __shared__ int hcnt[512];
    const int c = blockIdx.x, t = threadIdx.x;
    for (int b = t; b < nbucket; b += 256) hcnt[b] = 0;
    __syncthreads();
    const int base = c * CHUNK;
    for (int i = t * 4; i < CHUNK; i += 1024) {
        int e = base + i;
        if (e + 3 < E) {
            int4 d = *(const int4*)(dst + e);
            atomicAdd(&hcnt[d.x >> BSHIFT], 1);
            atomicAdd(&hcnt[d.y >> BSHIFT], 1);
            atomicAdd(&hcnt[d.z >> BSHIFT], 1);
            atomicAdd(&hcnt[d.w >> BSHIFT], 1);
        } else {
            for (int j = e; j < E; ++j) atomicAdd(&hcnt[dst[j] >> BSHIFT], 1);
        }
    }
    __syncthreads();
    for (int b = t; b < nbucket; b += 256) histT[b * nchunk + c] = hcnt[b];
}

// ---------------------------------------------------------------------------
// K2a/b/c: parallel exclusive scan over histT (total entries) + sentinel
// ---------------------------------------------------------------------------
__global__ __launch_bounds__(256) void scan_a_k(int* __restrict__ h,
                                                int* __restrict__ blksum, int total) {
    __shared__ int s[256];
    int t = threadIdx.x;
    int base = blockIdx.x * 1024 + t * 4;
    int v0 = 0, v1 = 0, v2 = 0, v3 = 0;
    if (base + 3 < total) {
        int4 q = *(const int4*)(h + base);
        v0 = q.x; v1 = q.y; v2 = q.z; v3 = q.w;
    } else {
        if (base     < total) v0 = h[base];
        if (base + 1 < total) v1 = h[base + 1];
        if (base + 2 < total) v2 = h[base + 2];
        if (base + 3 < total) v3 = h[base + 3];
    }
    int tsum = v0 + v1 + v2 + v3;
    s[t] = tsum;
    __syncthreads();
    for (int o = 1; o < 256; o <<= 1) {
        int x = (t >= o) ? s[t - o] : 0;
        __syncthreads();
        s[t] += x;
        __syncthreads();
    }
    int excl = s[t] - tsum;
    if (t == 255) blksum[blockIdx.x] = s[255];
    int e0 = excl, e1 = e0 + v0, e2 = e1 + v1, e3 = e2 + v2;
    if (base     < total) h[base]     = e0;
    if (base + 1 < total) h[base + 1] = e1;
    if (base + 2 < total) h[base + 2] = e2;
    if (base + 3 < total) h[base + 3] = e3;
}

__global__ __launch_bounds__(256) void scan_b_k(int* __restrict__ blksum, int NB) {
    __shared__ int s[256];
    int t = threadIdx.x;
    int v = (t < NB) ? blksum[t] : 0;
    s[t] = v;
    __syncthreads();
    for (int o = 1; o < 256; o <<= 1) {
        int x = (t >= o) ? s[t - o] : 0;
        __syncthreads();
        s[t] += x;
        __syncthreads();
    }
    if (t < NB) blksum[t] = s[t] - v;   // exclusive
}

__global__ __launch_bounds__(256) void scan_c_k(int* __restrict__ h,
                                                const int* __restrict__ blksum,
                                                int total, int E) {
    int i = blockIdx.x * 256 + threadIdx.x;
    if (i < total) h[i] += blksum[blockIdx.x >> 2];
    if (i == 0) h[total] = E;           // sentinel
}

// ---------------------------------------------------------------------------
// K3: partition edges into bucket-grouped runs. pack = src | (dst&255)<<20
// ---------------------------------------------------------------------------
__global__ __launch_bounds__(256) void partition_k(
    const int* __restrict__ src, const int* __restrict__ dst,
    const int* __restrict__ scanned, unsigned int* __restrict__ pack,
    int E, int nchunk, int nbucket) {
    __shared__ int basebc[512];
    __shared__ int cur[512];
    const int c = blockIdx.x, t = threadIdx.x;
    for (int b = t; b < nbucket; b += 256) {
        basebc[b] = scanned[b * nchunk + c];
        cur[b] = 0;
    }
    __syncthreads();
    const int base = c * CHUNK;
    for (int i = t * 4; i < CHUNK; i += 1024) {
        int e = base + i;
        if (e + 3 < E) {
            int4 sv = *(const int4*)(src + e);
            int4 dv = *(const int4*)(dst + e);
            int b0 = dv.x >> BSHIFT, b1 = dv.y >> BSHIFT;
            int b2 = dv.z >> BSHIFT, b3 = dv.w >> BSHIFT;
            int p0 = basebc[b0] + atomicAdd(&cur[b0], 1);
            int p1 = basebc[b1] + atomicAdd(&cur[b1], 1);
            int p2 = basebc[b2] + atomicAdd(&cur[b2], 1);
            int p3 = basebc[b3] + atomicAdd(&cur[b3], 1);
            pack[p0] = (unsigned)sv.x | ((unsigned)(dv.x & 255) << 20);
            pack[p1] = (unsigned)sv.y | ((unsigned)(dv.y & 255) << 20);
            pack[p2] = (unsigned)sv.z | ((unsigned)(dv.z & 255) << 20);
            pack[p3] = (unsigned)sv.w | ((unsigned)(dv.w & 255) << 20);
        } else {
            for (int j = e; j < E; ++j) {
                int d = dst[j];
                int b = d >> BSHIFT;
                int p = basebc[b] + atomicAdd(&cur[b], 1);
                pack[p] = (unsigned)src[j] | ((unsigned)(d & 255) << 20);
            }
        }
    }
}

// ---------------------------------------------------------------------------
// K4: per-bucket LDS counting sort by dst&255 -> dst-sorted CSR + cnt/offs/dinv
// ---------------------------------------------------------------------------
__global__ __launch_bounds__(256) void bucket_k(
    const unsigned int* __restrict__ pack, const int* __restrict__ scanned,
    int* __restrict__ csr, int* __restrict__ offs_g, int* __restrict__ cnt_g,
    float* __restrict__ dinv, int N, int nchunk) {
    __shared__ unsigned int arr[BCAP];
    __shared__ unsigned int csr_l[BCAP];
    __shared__ int cnt[256], off[256], cur[256], sscan[256];
    const int b = blockIdx.x, t = threadIdx.x;
    const int base = scanned[b * nchunk];
    int cb = scanned[(b + 1) * nchunk] - base;
    if (cb > BCAP) cb = BCAP;   // never happens for this input
    for (int i = t; i < cb; i += 256) arr[i] = pack[base + i];
    cnt[t] = 0; cur[t] = 0;
    __syncthreads();
    for (int i = t; i < cb; i += 256) atomicAdd(&cnt[arr[i] >> 20], 1);
    __syncthreads();
    int v = cnt[t];
    sscan[t] = v;
    __syncthreads();
    for (int o = 1; o < 256; o <<= 1) {
        int x = (t >= o) ? sscan[t - o] : 0;
        __syncthreads();
        sscan[t] += x;
        __syncthreads();
    }
    off[t] = sscan[t] - v;
    __syncthreads();
    for (int i = t; i < cb; i += 256) {
        unsigned int a = arr[i];
        int dl = a >> 20;
        int p = off[dl] + atomicAdd(&cur[dl], 1);
        csr_l[p] = a & 0xFFFFFu;
    }
    __syncthreads();
    for (int i = t; i < cb; i += 256) csr[base + i] = (int)csr_l[i];
    int node = (b << BSHIFT) + t;
    if (node < N) {
        cnt_g[node]  = cnt[t];
        offs_g[node] = base + off[t];
        dinv[node]   = rsqrtf((float)cnt[t] + 1.0f);
    }
}

// ---------------------------------------------------------------------------
// W1 cast: [192][128] f32 -> transposed hi/lo bf16 [128 cols][192 k]
// ---------------------------------------------------------------------------
__global__ __launch_bounds__(256) void w1cast_k(const float* __restrict__ W1,
                                                unsigned short* __restrict__ Whi,
                                                unsigned short* __restrict__ Wlo) {
    int t = blockIdx.x * 256 + threadIdx.x;   // 0 .. 192*128-1
    if (t >= 192 * 128) return;
    int k = t >> 7, c = t & 127;
    float v = W1[t];
    unsigned short hi = f2bf(v);
    float lo = v - bf2f(hi);
    Whi[c * 192 + k] = hi;
    Wlo[c * 192 + k] = f2bf(lo);
}

// ---------------------------------------------------------------------------
// GEMM1 (MFMA, 2-term split): h1s = ([uY|X] @ W1) * dinv, bf16 out
// a*b ~= ah*(bh+bl): A-quantization error ~2^-9 rel == output bf16 rounding.
// LDS 48.5 KB -> 3 blocks/CU.
// ---------------------------------------------------------------------------
__global__ __launch_bounds__(256) void gemm1_mfma_k(
    const float* __restrict__ uY, const float* __restrict__ X,
    const unsigned short* __restrict__ Whi, const unsigned short* __restrict__ Wlo,
    const float* __restrict__ dinv, unsigned short* __restrict__ h1s, int N) {
    __shared__ unsigned short Ah[128 * 64];
    __shared__ unsigned short Bh[128 * 64];
    __shared__ unsigned short Bl[128 * 64];
    __shared__ float dvs[128];
    const int t = threadIdx.x;
    const int wave = t >> 6, lane = t & 63;
    const int lr = lane & 15, lg = lane >> 4;
    const int nb = blockIdx.x * 128;

    if (t < 128) {
        int node = nb + t;
        dvs[t] = (node < N) ? dinv[node] : 0.0f;
    }

    f32x4 acc[2][8];
    for (int i = 0; i < 2; ++i)
        for (int j = 0; j < 8; ++j)
            for (int e = 0; e < 4; ++e) acc[i][j][e] = 0.0f;

    for (int chunk = 0; chunk < 3; ++chunk) {
        const float* sp = (chunk == 0) ? uY : X;
        const int stride = (chunk == 0) ? 64 : 128;
        const int coloff = (chunk == 0) ? 0 : (chunk - 1) * 64;
        // stage A (hi only): 128 rows x 64 k floats = 8192 = 8 x 256thr x 4
        for (int it = 0; it < 8; ++it) {
            int flat = (it * 256 + t) * 4;
            int r = flat >> 6, k = flat & 63;
            int node = nb + r;
            float4 v = make_float4(0.f, 0.f, 0.f, 0.f);
            if (node < N) v = *(const float4*)(sp + (size_t)node * stride + coloff + k);
            int boff = (r * 128 + k * 2) ^ ((r & 7) << 4);
            *(uint2*)((char*)Ah + boff) =
                make_uint2((unsigned)f2bf(v.x) | ((unsigned)f2bf(v.y) << 16),
                           (unsigned)f2bf(v.z) | ((unsigned)f2bf(v.w) << 16));
        }
        // stage B (hi + lo)
#pragma unroll
        for (int it = 0; it < 4; ++it) {
            int idx = it * 256 + t;
            int c = idx >> 3, kb = (idx & 7) * 8;
            int goff = c * 192 + chunk * 64 + kb;
            uint4 hv = *(const uint4*)(Whi + goff);
            uint4 lv = *(const uint4*)(Wlo + goff);
            int boff = (c * 128 + kb * 2) ^ ((c & 7) << 4);
            *(uint4*)((char*)Bh + boff) = hv;
            *(uint4*)((char*)Bl + boff) = lv;
        }
        __syncthreads();

#pragma unroll
        for (int ks = 0; ks < 2; ++ks) {
            short8v afh[2];
#pragma unroll
            for (int mf = 0; mf < 2; ++mf) {
                int r = wave * 32 + mf * 16 + lr;
                int k = ks * 32 + lg * 8;
                int boff = (r * 128 + k * 2) ^ ((r & 7) << 4);
                afh[mf] = *(short8v*)((char*)Ah + boff);
            }
#pragma unroll
            for (int nf = 0; nf < 8; ++nf) {
                int c = nf * 16 + lr;
                int k = ks * 32 + lg * 8;
                int boff = (c * 128 + k * 2) ^ ((c & 7) << 4);
                short8v bh = *(short8v*)((char*)Bh + boff);
                short8v bl = *(short8v*)((char*)Bl + boff);
#pragma unroll
                for (int mf = 0; mf < 2; ++mf) {
                    acc[mf][nf] = __builtin_amdgcn_mfma_f32_16x16x32_bf16(afh[mf], bh, acc[mf][nf], 0, 0, 0);
                    acc[mf][nf] = __builtin_amdgcn_mfma_f32_16x16x32_bf16(afh[mf], bl, acc[mf][nf], 0, 0, 0);
                }
            }
        }
        __syncthreads();
    }

    // C/D layout (m89): col = lane&15, row = (lane>>4)*4 + reg
#pragma unroll
    for (int mf = 0; mf < 2; ++mf) {
#pragma unroll
        for (int r2 = 0; r2 < 4; ++r2) {
            int row = wave * 32 + mf * 16 + lg * 4 + r2;
            int node = nb + row;
            if (node >= N) continue;
            float dv = dvs[row];
#pragma unroll
            for (int nf = 0; nf < 8; ++nf) {
                int col = nf * 16 + lr;
                h1s[(size_t)node * 128 + col] = f2bf(acc[mf][nf][r2] * dv);
            }
        }
    }
}

// ---------------------------------------------------------------------------
// aggregate1 by gather (bf16 rows): one wave per node, lane = 2 channels
// 8 edges in flight per iteration
// ---------------------------------------------------------------------------
__global__ __launch_bounds__(256) void agg1_gather_k(
    const int* __restrict__ csr, const int* __restrict__ offs,
    const int* __restrict__ cnt, const float* __restrict__ dinv,
    const unsigned int* __restrict__ h1s, unsigned int* __restrict__ out1, int N) {
    int node = blockIdx.x * 4 + (threadIdx.x >> 6);
    if (node >= N) return;
    int lane = threadIdx.x & 63;
    int beg = offs[node], num = cnt[node];
    unsigned int w = h1s[(size_t)node * 64 + lane];
    float ax = bf2f(w & 0xFFFFu), ay = bf2f(w >> 16);
    int i = 0;
    for (; i + 7 < num; i += 8) {
        unsigned int wv[8];
#pragma unroll
        for (int j = 0; j < 8; ++j) {
            int s = csr[beg + i + j];
            wv[j] = h1s[(size_t)s * 64 + lane];
        }
#pragma unroll
        for (int j = 0; j < 8; ++j) {
            ax += bf2f(wv[j] & 0xFFFFu);
            ay += bf2f(wv[j] >> 16);
        }
    }
    for (; i < num; ++i) {
        unsigned int w0 = h1s[(size_t)csr[beg + i] * 64 + lane];
        ax += bf2f(w0 & 0xFFFFu);
        ay += bf2f(w0 >> 16);
    }
    float dd = dinv[node];
    out1[(size_t)node * 64 + lane] = pack2bf(ax * dd, ay * dd);
}

// ---------------------------------------------------------------------------
// BN1 stats over bf16 out1: per-channel sum & sumsq
// ---------------------------------------------------------------------------
__global__ __launch_bounds__(256) void bn1_stats_k(const unsigned int* __restrict__ out1,
                                                   float* __restrict__ stats, int N) {
    __shared__ float4 ssum[256];
    __shared__ float4 ssq[256];
    int t = threadIdx.x;
    int c4 = t & 31, r = t >> 5;
    float4 sum = make_float4(0.f, 0.f, 0.f, 0.f);
    float4 sq  = make_float4(0.f, 0.f, 0.f, 0.f);
    for (int n = blockIdx.x * 8 + r; n < N; n += gridDim.x * 8) {
        uint2 w = *(const uint2*)(out1 + (size_t)n * 64 + c4 * 2);
        float v0 = bf2f(w.x & 0xFFFFu), v1 = bf2f(w.x >> 16);
        float v2 = bf2f(w.y & 0xFFFFu), v3 = bf2f(w.y >> 16);
        sum.x += v0; sum.y += v1; sum.z += v2; sum.w += v3;
        sq.x += v0 * v0; sq.y += v1 * v1; sq.z += v2 * v2; sq.w += v3 * v3;
    }
    ssum[t] = sum; ssq[t] = sq;
    __syncthreads();
    for (int sft = 128; sft >= 32; sft >>= 1) {
        if (t < sft) {
            ssum[t].x += ssum[t + sft].x; ssum[t].y += ssum[t + sft].y;
            ssum[t].z += ssum[t + sft].z; ssum[t].w += ssum[t + sft].w;
            ssq[t].x  += ssq[t + sft].x;  ssq[t].y  += ssq[t + sft].y;
            ssq[t].z  += ssq[t + sft].z;  ssq[t].w  += ssq[t + sft].w;
        }
        __syncthreads();
    }
    if (t < 32) {
        float4 a = ssum[t], b = ssq[t];
        atomicAdd(&stats[t * 4 + 0], a.x); atomicAdd(&stats[t * 4 + 1], a.y);
        atomicAdd(&stats[t * 4 + 2], a.z); atomicAdd(&stats[t * 4 + 3], a.w);
        atomicAdd(&stats[128 + t * 4 + 0], b.x); atomicAdd(&stats[128 + t * 4 + 1], b.y);
        atomicAdd(&stats[128 + t * 4 + 2], b.z); atomicAdd(&stats[128 + t * 4 + 3], b.w);
    }
}

__global__ void bn1_final_k(const float* __restrict__ stats,
                            const float* __restrict__ gamma1,
                            const float* __restrict__ beta1,
                            float* __restrict__ bn1, float invN) {
    int c = threadIdx.x;
    float mean = stats[c] * invN;
    float var  = stats[128 + c] * invN - mean * mean;
    float a = gamma1[c] * rsqrtf(var + BN_EPS);
    bn1[c] = a;
    bn1[128 + c] = beta1[c] - mean * a;
}

// ---------------------------------------------------------------------------
// GEMM2 fused: y = relu(BN1(out1)); h2s = (y @ W2) * dinv ; wave per node
// ---------------------------------------------------------------------------
__global__ __launch_bounds__(256) void gemm2_k(
    const unsigned int* __restrict__ out1, const float* __restrict__ bn1,
    const float* __restrict__ W2, const float* __restrict__ dinv,
    float* __restrict__ h2s, int N) {
    int node = blockIdx.x * 4 + (threadIdx.x >> 6);
    if (node >= N) return;
    int lane = threadIdx.x & 63;
    unsigned int w = out1[(size_t)node * 64 + lane];
    int c0 = lane * 2, c1 = lane * 2 + 1;
    float v0 = bf2f(w & 0xFFFFu), v1 = bf2f(w >> 16);
    float y0 = fmaxf(fmaf(bn1[c0], v0, bn1[128 + c0]), 0.f);
    float y1 = fmaxf(fmaf(bn1[c1], v1, bn1[128 + c1]), 0.f);
    float4 w2 = *(const float4*)(W2 + c0 * 2);   // rows c0,c1 of [128][2]
    float acc0 = y0 * w2.x + y1 * w2.z;
    float acc1 = y0 * w2.y + y1 * w2.w;
    for (int off = 32; off; off >>= 1) {
        acc0 += __shfl_xor(acc0, off);
        acc1 += __shfl_xor(acc1, off);
    }
    if (lane == 0) {
        float dv = dinv[node];
        *(float2*)(h2s + (size_t)node * 2) = make_float2(acc0 * dv, acc1 * dv);
    }
}

// aggregate2 by gather: one thread per node, both channels
__global__ __launch_bounds__(256) void agg2_gather_k(
    const int* __restrict__ csr, const int* __restrict__ offs,
    const int* __restrict__ cnt, const float* __restrict__ dinv,
    const float* __restrict__ h2s, float* __restrict__ out2, int N) {
    int node = blockIdx.x * 256 + threadIdx.x;
    if (node >= N) return;
    int beg = offs[node], num = cnt[node];
    float2 acc = *(const float2*)(h2s + (size_t)node * 2);
    for (int i = 0; i < num; ++i) {
        int s = csr[beg + i];
        float2 v = *(const float2*)(h2s + (size_t)s * 2);
        acc.x += v.x;
        acc.y += v.y;
    }
    float dd = dinv[node];
    *(float2*)(out2 + (size_t)node * 2) = make_float2(acc.x * dd, acc.y * dd);
}

// BN2 stats
__global__ __launch_bounds__(256) void bn2_stats_k(const float* __restrict__ out2,
                                                   float* __restrict__ stats, int N) {
    __shared__ float4 red[256];
    int t = threadIdx.x;
    float4 acc = make_float4(0.f, 0.f, 0.f, 0.f);
    for (int n = blockIdx.x * 256 + t; n < N; n += gridDim.x * 256) {
        float2 v = *(const float2*)(out2 + (size_t)n * 2);
        acc.x += v.x; acc.y += v.y; acc.z += v.x * v.x; acc.w += v.y * v.y;
    }
    red[t] = acc;
    __syncthreads();
    for (int s = 128; s; s >>= 1) {
        if (t < s) {
            red[t].x += red[t + s].x; red[t].y += red[t + s].y;
            red[t].z += red[t + s].z; red[t].w += red[t + s].w;
        }
        __syncthreads();
    }
    if (t == 0) {
        atomicAdd(&stats[0], red[0].x); atomicAdd(&stats[1], red[0].y);
        atomicAdd(&stats[2], red[0].z); atomicAdd(&stats[3], red[0].w);
    }
}

// final: BN2 + softmax(2)
__global__ __launch_bounds__(256) void final_k(
    const float* __restrict__ out2, const float* __restrict__ stats,
    const float* __restrict__ gamma2, const float* __restrict__ beta2,
    float* __restrict__ outp, int N, float invN) {
    int i = blockIdx.x * 256 + threadIdx.x;
    if (i >= N) return;
    float m0 = stats[0] * invN, m1 = stats[1] * invN;
    float var0 = stats[2] * invN - m0 * m0;
    float var1 = stats[3] * invN - m1 * m1;
    float a0 = gamma2[0] * rsqrtf(var0 + BN_EPS);
    float a1 = gamma2[1] * rsqrtf(var1 + BN_EPS);
    float c0 = beta2[0] - m0 * a0;
    float c1 = beta2[1] - m1 * a1;
    float2 v = *(const float2*)(out2 + (size_t)i * 2);
    float y0 = fmaf(a0, v.x, c0);
    float y1 = fmaf(a1, v.y, c1);
    float mx = fmaxf(y0, y1);
    float e0 = expf(y0 - mx), e1 = expf(y1 - mx);
    float inv = 1.f / (e0 + e1);
    *(float2*)(outp + (size_t)i * 2) = make_float2(e0 * inv, e1 * inv);
}

// ---------------------------------------------------------------------------
extern "C" void kernel_launch(void* const* d_in, const int* in_sizes, int n_in,
                              void* d_out, int out_size, void* d_ws, size_t ws_size,
                              hipStream_t stream) {
    const int*   edge   = (const int*)d_in[0];
    const float* X      = (const float*)d_in[1];
    const float* uY     = (const float*)d_in[2];
    const float* W1     = (const float*)d_in[3];
    // b1/b2 cancel under BatchNorm -- skipped
    const float* W2     = (const float*)d_in[5];
    const float* gamma1 = (const float*)d_in[7];
    const float* beta1  = (const float*)d_in[8];
    const float* gamma2 = (const float*)d_in[9];
    const float* beta2  = (const float*)d_in[10];

    const int E = in_sizes[0] / 2;
    const int N = in_sizes[1] / 128;
    const int* srcI = edge;
    const int* dstI = edge + E;

    const int nchunk  = (E + CHUNK - 1) / CHUNK;
    const int nbucket = (N + 255) >> BSHIFT;
    const int total   = nbucket * nchunk;
    const int nscan   = (total + 1023) / 1024;   // scan blocks (<=256)

    // workspace layout (4-byte words):
    // stats1[256] bn1[256] stats2[64] Whi[6144w] Wlo[6144w] blksum[256]
    // h1s[N*64] out1[N*64] dinv[N] h2s[2N] out2[2N] cnt[N] offs[N]
    // histT[total+1] pack[E] csr[E]
    float* stats1 = (float*)d_ws;
    float* bn1    = stats1 + 256;
    float* stats2 = bn1 + 256;
    unsigned short* Whi = (unsigned short*)(stats2 + 64);     // 128*192 bf16
    unsigned short* Wlo = Whi + 128 * 192;
    int*   blksum = (int*)(Wlo + 128 * 192);
    unsigned int* h1s  = (unsigned int*)(blksum + 256);
    unsigned int* out1 = h1s + (size_t)N * 64;
    float* dinv   = (float*)(out1 + (size_t)N * 64);
    float* h2s    = dinv + N;
    float* out2   = h2s + (size_t)N * 2;
    int*   cnt    = (int*)(out2 + (size_t)N * 2);
    int*   offs   = cnt + N;
    int*   histT  = offs + N;
    unsigned int* pack = (unsigned int*)(histT + total + 1);
    int*   csr    = (int*)(pack + E);

    hipMemsetAsync(stats1, 0, 256 * sizeof(float), stream);
    hipMemsetAsync(stats2, 0, 4 * sizeof(float), stream);

    // CSR build: histogram -> parallel scan -> partition -> per-bucket sort
    hist_k<<<nchunk, 256, 0, stream>>>(dstI, histT, E, nchunk, nbucket);
    scan_a_k<<<nscan, 256, 0, stream>>>(histT, blksum, total);
    scan_b_k<<<1, 256, 0, stream>>>(blksum, nscan);
    scan_c_k<<<nscan * 4, 256, 0, stream>>>(histT, blksum, total, E);
    partition_k<<<nchunk, 256, 0, stream>>>(srcI, dstI, histT, pack, E, nchunk, nbucket);
    bucket_k<<<nbucket, 256, 0, stream>>>(pack, histT, csr, offs, cnt, dinv, N, nchunk);

    w1cast_k<<<(192 * 128 + 255) / 256, 256, 0, stream>>>(W1, Whi, Wlo);
    gemm1_mfma_k<<<(N + 127) / 128, 256, 0, stream>>>(uY, X, Whi, Wlo, dinv,
                                                      (unsigned short*)h1s, N);
    agg1_gather_k<<<(N + 3) / 4, 256, 0, stream>>>(csr, offs, cnt, dinv, h1s, out1, N);
    bn1_stats_k<<<512, 256, 0, stream>>>(out1, stats1, N);
    bn1_final_k<<<1, 128, 0, stream>>>(stats1, gamma1, beta1, bn1, 1.0f / N);
    gemm2_k<<<(N + 3) / 4, 256, 0, stream>>>(out1, bn1, W2, dinv, h2s, N);
    agg2_gather_k<<<(N + 255) / 256, 256, 0, stream>>>(csr, offs, cnt, dinv, h2s, out2, N);
    bn2_stats_k<<<256, 256, 0, stream>>>(out2, stats2, N);
    final_k<<<(N + 255) / 256, 256, 0, stream>>>(out2, stats2, gamma2, beta2,
                                                 (float*)d_out, N, 1.0f / N);
}

// Round 14
// 382.773 us; speedup vs baseline: 4.7989x; 1.0193x over previous
//
#include <hip/hip_runtime.h>
#include <math.h>

#define BN_EPS 1e-5f
#define CHUNK 8192           // edges per partition chunk
#define BSHIFT 8             // 256 nodes per bucket
#define BCAP 6144            // max edges per bucket (avg 4096; +32 sigma slack)

typedef __attribute__((ext_vector_type(8))) short short8v;
typedef __attribute__((ext_vector_type(4))) float f32x4;

__device__ __forceinline__ unsigned short f2bf(float x) {
    unsigned int u = __float_as_uint(x);
    u += 0x7FFFu + ((u >> 16) & 1u);     // RNE
    return (unsigned short)(u >> 16);
}
__device__ __forceinline__ float bf2f(unsigned int u16) {
    return __uint_as_float(u16 << 16);
}
__device__ __forceinline__ unsigned int pack2bf(float a, float b) {
    return (unsigned int)f2bf(a) | ((unsigned int)f2bf(b) << 16);
}

// ---------------------------------------------------------------------------
// K1: per-chunk histogram over dst buckets (dst>>8).  histT[b*nchunk + c]
// ---------------------------------------------------------------------------
__global__ __launch_bounds__(256) void hist_k(const int* __restrict__ dst,
                                              int* __restrict__ histT,
                                              int E, int nchunk, int nbucket) {
    __shared__ int hcnt[512];
    const int c = blockIdx.x, t = threadIdx.x;
    for (int b = t; b < nbucket; b += 256) hcnt[b] = 0;
    __syncthreads();
    const int base = c * CHUNK;
    for (int i = t * 4; i < CHUNK; i += 1024) {
        int e = base + i;
        if (e + 3 < E) {
            int4 d = *(const int4*)(dst + e);
            atomicAdd(&hcnt[d.x >> BSHIFT], 1);
            atomicAdd(&hcnt[d.y >> BSHIFT], 1);
            atomicAdd(&hcnt[d.z >> BSHIFT], 1);
            atomicAdd(&hcnt[d.w >> BSHIFT], 1);
        } else {
            for (int j = e; j < E; ++j) atomicAdd(&hcnt[dst[j] >> BSHIFT], 1);
        }
    }
    __syncthreads();
    for (int b = t; b < nbucket; b += 256) histT[b * nchunk + c] = hcnt[b];
}

// ---------------------------------------------------------------------------
// K2a/b/c: parallel exclusive scan over histT (total entries) + sentinel
// ---------------------------------------------------------------------------
__global__ __launch_bounds__(256) void scan_a_k(int* __restrict__ h,
                                                int* __restrict__ blksum, int total) {
    __shared__ int s[256];
    int t = threadIdx.x;
    int base = blockIdx.x * 1024 + t * 4;
    int v0 = 0, v1 = 0, v2 = 0, v3 = 0;
    if (base + 3 < total) {
        int4 q = *(const int4*)(h + base);
        v0 = q.x; v1 = q.y; v2 = q.z; v3 = q.w;
    } else {
        if (base     < total) v0 = h[base];
        if (base + 1 < total) v1 = h[base + 1];
        if (base + 2 < total) v2 = h[base + 2];
        if (base + 3 < total) v3 = h[base + 3];
    }
    int tsum = v0 + v1 + v2 + v3;
    s[t] = tsum;
    __syncthreads();
    for (int o = 1; o < 256; o <<= 1) {
        int x = (t >= o) ? s[t - o] : 0;
        __syncthreads();
        s[t] += x;
        __syncthreads();
    }
    int excl = s[t] - tsum;
    if (t == 255) blksum[blockIdx.x] = s[255];
    int e0 = excl, e1 = e0 + v0, e2 = e1 + v1, e3 = e2 + v2;
    if (base     < total) h[base]     = e0;
    if (base + 1 < total) h[base + 1] = e1;
    if (base + 2 < total) h[base + 2] = e2;
    if (base + 3 < total) h[base + 3] = e3;
}

__global__ __launch_bounds__(256) void scan_b_k(int* __restrict__ blksum, int NB) {
    __shared__ int s[256];
    int t = threadIdx.x;
    int v = (t < NB) ? blksum[t] : 0;
    s[t] = v;
    __syncthreads();
    for (int o = 1; o < 256; o <<= 1) {
        int x = (t >= o) ? s[t - o] : 0;
        __syncthreads();
        s[t] += x;
        __syncthreads();
    }
    if (t < NB) blksum[t] = s[t] - v;   // exclusive
}

__global__ __launch_bounds__(256) void scan_c_k(int* __restrict__ h,
                                                const int* __restrict__ blksum,
                                                int total, int E) {
    int i = blockIdx.x * 256 + threadIdx.x;
    if (i < total) h[i] += blksum[blockIdx.x >> 2];
    if (i == 0) h[total] = E;           // sentinel
}

// ---------------------------------------------------------------------------
// K3: partition edges into bucket-grouped runs. pack = src | (dst&255)<<20
// ---------------------------------------------------------------------------
__global__ __launch_bounds__(256) void partition_k(
    const int* __restrict__ src, const int* __restrict__ dst,
    const int* __restrict__ scanned, unsigned int* __restrict__ pack,
    int E, int nchunk, int nbucket) {
    __shared__ int basebc[512];
    __shared__ int cur[512];
    const int c = blockIdx.x, t = threadIdx.x;
    for (int b = t; b < nbucket; b += 256) {
        basebc[b] = scanned[b * nchunk + c];
        cur[b] = 0;
    }
    __syncthreads();
    const int base = c * CHUNK;
    for (int i = t * 4; i < CHUNK; i += 1024) {
        int e = base + i;
        if (e + 3 < E) {
            int4 sv = *(const int4*)(src + e);
            int4 dv = *(const int4*)(dst + e);
            int b0 = dv.x >> BSHIFT, b1 = dv.y >> BSHIFT;
            int b2 = dv.z >> BSHIFT, b3 = dv.w >> BSHIFT;
            int p0 = basebc[b0] + atomicAdd(&cur[b0], 1);
            int p1 = basebc[b1] + atomicAdd(&cur[b1], 1);
            int p2 = basebc[b2] + atomicAdd(&cur[b2], 1);
            int p3 = basebc[b3] + atomicAdd(&cur[b3], 1);
            pack[p0] = (unsigned)sv.x | ((unsigned)(dv.x & 255) << 20);
            pack[p1] = (unsigned)sv.y | ((unsigned)(dv.y & 255) << 20);
            pack[p2] = (unsigned)sv.z | ((unsigned)(dv.z & 255) << 20);
            pack[p3] = (unsigned)sv.w | ((unsigned)(dv.w & 255) << 20);
        } else {
            for (int j = e; j < E; ++j) {
                int d = dst[j];
                int b = d >> BSHIFT;
                int p = basebc[b] + atomicAdd(&cur[b], 1);
                pack[p] = (unsigned)src[j] | ((unsigned)(d & 255) << 20);
            }
        }
    }
}

// ---------------------------------------------------------------------------
// K4: per-bucket LDS counting sort by dst&255 -> dst-sorted CSR + cnt/offs/dinv
// CSR written directly (block-private 16KB region -> L2 write-combines)
// ---------------------------------------------------------------------------
__global__ __launch_bounds__(256) void bucket_k(
    const unsigned int* __restrict__ pack, const int* __restrict__ scanned,
    int* __restrict__ csr, int* __restrict__ offs_g, int* __restrict__ cnt_g,
    float* __restrict__ dinv, int N, int nchunk) {
    __shared__ unsigned int arr[BCAP];
    __shared__ int cnt[256], off[256], cur[256], sscan[256];
    const int b = blockIdx.x, t = threadIdx.x;
    const int base = scanned[b * nchunk];
    int cb = scanned[(b + 1) * nchunk] - base;
    if (cb > BCAP) cb = BCAP;   // never happens for this input
    for (int i = t; i < cb; i += 256) arr[i] = pack[base + i];
    cnt[t] = 0; cur[t] = 0;
    __syncthreads();
    for (int i = t; i < cb; i += 256) atomicAdd(&cnt[arr[i] >> 20], 1);
    __syncthreads();
    int v = cnt[t];
    sscan[t] = v;
    __syncthreads();
    for (int o = 1; o < 256; o <<= 1) {
        int x = (t >= o) ? sscan[t - o] : 0;
        __syncthreads();
        sscan[t] += x;
        __syncthreads();
    }
    off[t] = sscan[t] - v;
    __syncthreads();
    for (int i = t; i < cb; i += 256) {
        unsigned int a = arr[i];
        int dl = a >> 20;
        int p = off[dl] + atomicAdd(&cur[dl], 1);
        csr[base + p] = (int)(a & 0xFFFFFu);    // direct, block-private region
    }
    int node = (b << BSHIFT) + t;
    if (node < N) {
        cnt_g[node]  = cnt[t];
        offs_g[node] = base + off[t];
        dinv[node]   = rsqrtf((float)cnt[t] + 1.0f);
    }
}

// ---------------------------------------------------------------------------
// W1 cast: [192][128] f32 -> transposed hi/lo bf16 [128 cols][192 k]
// ---------------------------------------------------------------------------
__global__ __launch_bounds__(256) void w1cast_k(const float* __restrict__ W1,
                                                unsigned short* __restrict__ Whi,
                                                unsigned short* __restrict__ Wlo) {
    int t = blockIdx.x * 256 + threadIdx.x;   // 0 .. 192*128-1
    if (t >= 192 * 128) return;
    int k = t >> 7, c = t & 127;
    float v = W1[t];
    unsigned short hi = f2bf(v);
    float lo = v - bf2f(hi);
    Whi[c * 192 + k] = hi;
    Wlo[c * 192 + k] = f2bf(lo);
}

// ---------------------------------------------------------------------------
// GEMM1 (MFMA, 2-term split): h1s = ([uY|X] @ W1) * dinv, bf16 out
// ---------------------------------------------------------------------------
__global__ __launch_bounds__(256) void gemm1_mfma_k(
    const float* __restrict__ uY, const float* __restrict__ X,
    const unsigned short* __restrict__ Whi, const unsigned short* __restrict__ Wlo,
    const float* __restrict__ dinv, unsigned short* __restrict__ h1s, int N) {
    __shared__ unsigned short Ah[128 * 64];
    __shared__ unsigned short Bh[128 * 64];
    __shared__ unsigned short Bl[128 * 64];
    __shared__ float dvs[128];
    const int t = threadIdx.x;
    const int wave = t >> 6, lane = t & 63;
    const int lr = lane & 15, lg = lane >> 4;
    const int nb = blockIdx.x * 128;

    if (t < 128) {
        int node = nb + t;
        dvs[t] = (node < N) ? dinv[node] : 0.0f;
    }

    f32x4 acc[2][8];
    for (int i = 0; i < 2; ++i)
        for (int j = 0; j < 8; ++j)
            for (int e = 0; e < 4; ++e) acc[i][j][e] = 0.0f;

    for (int chunk = 0; chunk < 3; ++chunk) {
        const float* sp = (chunk == 0) ? uY : X;
        const int stride = (chunk == 0) ? 64 : 128;
        const int coloff = (chunk == 0) ? 0 : (chunk - 1) * 64;
        // stage A (hi only): 128 rows x 64 k floats = 8192 = 8 x 256thr x 4
        for (int it = 0; it < 8; ++it) {
            int flat = (it * 256 + t) * 4;
            int r = flat >> 6, k = flat & 63;
            int node = nb + r;
            float4 v = make_float4(0.f, 0.f, 0.f, 0.f);
            if (node < N) v = *(const float4*)(sp + (size_t)node * stride + coloff + k);
            int boff = (r * 128 + k * 2) ^ ((r & 7) << 4);
            *(uint2*)((char*)Ah + boff) =
                make_uint2((unsigned)f2bf(v.x) | ((unsigned)f2bf(v.y) << 16),
                           (unsigned)f2bf(v.z) | ((unsigned)f2bf(v.w) << 16));
        }
        // stage B (hi + lo)
#pragma unroll
        for (int it = 0; it < 4; ++it) {
            int idx = it * 256 + t;
            int c = idx >> 3, kb = (idx & 7) * 8;
            int goff = c * 192 + chunk * 64 + kb;
            uint4 hv = *(const uint4*)(Whi + goff);
            uint4 lv = *(const uint4*)(Wlo + goff);
            int boff = (c * 128 + kb * 2) ^ ((c & 7) << 4);
            *(uint4*)((char*)Bh + boff) = hv;
            *(uint4*)((char*)Bl + boff) = lv;
        }
        __syncthreads();

#pragma unroll
        for (int ks = 0; ks < 2; ++ks) {
            short8v afh[2];
#pragma unroll
            for (int mf = 0; mf < 2; ++mf) {
                int r = wave * 32 + mf * 16 + lr;
                int k = ks * 32 + lg * 8;
                int boff = (r * 128 + k * 2) ^ ((r & 7) << 4);
                afh[mf] = *(short8v*)((char*)Ah + boff);
            }
#pragma unroll
            for (int nf = 0; nf < 8; ++nf) {
                int c = nf * 16 + lr;
                int k = ks * 32 + lg * 8;
                int boff = (c * 128 + k * 2) ^ ((c & 7) << 4);
                short8v bh = *(short8v*)((char*)Bh + boff);
                short8v bl = *(short8v*)((char*)Bl + boff);
#pragma unroll
                for (int mf = 0; mf < 2; ++mf) {
                    acc[mf][nf] = __builtin_amdgcn_mfma_f32_16x16x32_bf16(afh[mf], bh, acc[mf][nf], 0, 0, 0);
                    acc[mf][nf] = __builtin_amdgcn_mfma_f32_16x16x32_bf16(afh[mf], bl, acc[mf][nf], 0, 0, 0);
                }
            }
        }
        __syncthreads();
    }

    // C/D layout (m89): col = lane&15, row = (lane>>4)*4 + reg
#pragma unroll
    for (int mf = 0; mf < 2; ++mf) {
#pragma unroll
        for (int r2 = 0; r2 < 4; ++r2) {
            int row = wave * 32 + mf * 16 + lg * 4 + r2;
            int node = nb + row;
            if (node >= N) continue;
            float dv = dvs[row];
#pragma unroll
            for (int nf = 0; nf < 8; ++nf) {
                int col = nf * 16 + lr;
                h1s[(size_t)node * 128 + col] = f2bf(acc[mf][nf][r2] * dv);
            }
        }
    }
}

// ---------------------------------------------------------------------------
// aggregate1 by gather (bf16 rows): one wave per node, lane = 2 channels
// ---------------------------------------------------------------------------
__global__ __launch_bounds__(256) void agg1_gather_k(
    const int* __restrict__ csr, const int* __restrict__ offs,
    const int* __restrict__ cnt, const float* __restrict__ dinv,
    const unsigned int* __restrict__ h1s, unsigned int* __restrict__ out1, int N) {
    int node = blockIdx.x * 4 + (threadIdx.x >> 6);
    if (node >= N) return;
    int lane = threadIdx.x & 63;
    int beg = offs[node], num = cnt[node];
    unsigned int w = h1s[(size_t)node * 64 + lane];
    float ax = bf2f(w & 0xFFFFu), ay = bf2f(w >> 16);
    int i = 0;
    for (; i + 7 < num; i += 8) {
        unsigned int wv[8];
#pragma unroll
        for (int j = 0; j < 8; ++j) {
            int s = csr[beg + i + j];
            wv[j] = h1s[(size_t)s * 64 + lane];
        }
#pragma unroll
        for (int j = 0; j < 8; ++j) {
            ax += bf2f(wv[j] & 0xFFFFu);
            ay += bf2f(wv[j] >> 16);
        }
    }
    for (; i < num; ++i) {
        unsigned int w0 = h1s[(size_t)csr[beg + i] * 64 + lane];
        ax += bf2f(w0 & 0xFFFFu);
        ay += bf2f(w0 >> 16);
    }
    float dd = dinv[node];
    out1[(size_t)node * 64 + lane] = pack2bf(ax * dd, ay * dd);
}

// ---------------------------------------------------------------------------
// BN1 stats over bf16 out1: per-channel sum & sumsq
// ---------------------------------------------------------------------------
__global__ __launch_bounds__(256) void bn1_stats_k(const unsigned int* __restrict__ out1,
                                                   float* __restrict__ stats, int N) {
    __shared__ float4 ssum[256];
    __shared__ float4 ssq[256];
    int t = threadIdx.x;
    int c4 = t & 31, r = t >> 5;
    float4 sum = make_float4(0.f, 0.f, 0.f, 0.f);
    float4 sq  = make_float4(0.f, 0.f, 0.f, 0.f);
    for (int n = blockIdx.x * 8 + r; n < N; n += gridDim.x * 8) {
        uint2 w = *(const uint2*)(out1 + (size_t)n * 64 + c4 * 2);
        float v0 = bf2f(w.x & 0xFFFFu), v1 = bf2f(w.x >> 16);
        float v2 = bf2f(w.y & 0xFFFFu), v3 = bf2f(w.y >> 16);
        sum.x += v0; sum.y += v1; sum.z += v2; sum.w += v3;
        sq.x += v0 * v0; sq.y += v1 * v1; sq.z += v2 * v2; sq.w += v3 * v3;
    }
    ssum[t] = sum; ssq[t] = sq;
    __syncthreads();
    for (int sft = 128; sft >= 32; sft >>= 1) {
        if (t < sft) {
            ssum[t].x += ssum[t + sft].x; ssum[t].y += ssum[t + sft].y;
            ssum[t].z += ssum[t + sft].z; ssum[t].w += ssum[t + sft].w;
            ssq[t].x  += ssq[t + sft].x;  ssq[t].y  += ssq[t + sft].y;
            ssq[t].z  += ssq[t + sft].z;  ssq[t].w  += ssq[t + sft].w;
        }
        __syncthreads();
    }
    if (t < 32) {
        float4 a = ssum[t], b = ssq[t];
        atomicAdd(&stats[t * 4 + 0], a.x); atomicAdd(&stats[t * 4 + 1], a.y);
        atomicAdd(&stats[t * 4 + 2], a.z); atomicAdd(&stats[t * 4 + 3], a.w);
        atomicAdd(&stats[128 + t * 4 + 0], b.x); atomicAdd(&stats[128 + t * 4 + 1], b.y);
        atomicAdd(&stats[128 + t * 4 + 2], b.z); atomicAdd(&stats[128 + t * 4 + 3], b.w);
    }
}

__global__ void bn1_final_k(const float* __restrict__ stats,
                            const float* __restrict__ gamma1,
                            const float* __restrict__ beta1,
                            float* __restrict__ bn1, float invN) {
    int c = threadIdx.x;
    float mean = stats[c] * invN;
    float var  = stats[128 + c] * invN - mean * mean;
    float a = gamma1[c] * rsqrtf(var + BN_EPS);
    bn1[c] = a;
    bn1[128 + c] = beta1[c] - mean * a;
}

// ---------------------------------------------------------------------------
// GEMM2 fused: y = relu(BN1(out1)); h2s = (y @ W2) * dinv
// 4 nodes per wave: 16-lane group per node, lane q handles channels 8q..8q+7
// ---------------------------------------------------------------------------
__global__ __launch_bounds__(256) void gemm2_k(
    const unsigned int* __restrict__ out1, const float* __restrict__ bn1,
    const float* __restrict__ W2, const float* __restrict__ dinv,
    float* __restrict__ h2s, int N) {
    int t = threadIdx.x;
    int wave = t >> 6, lane = t & 63;
    int grp = lane >> 4, q = lane & 15;
    int node = blockIdx.x * 16 + wave * 4 + grp;
    if (node >= N) return;
    uint4 v = *(const uint4*)(out1 + (size_t)node * 64 + q * 4);
    unsigned int ws[4] = {v.x, v.y, v.z, v.w};
    float acc0 = 0.f, acc1 = 0.f;
#pragma unroll
    for (int j = 0; j < 4; ++j) {
        int c0 = q * 8 + j * 2;
        float x0 = bf2f(ws[j] & 0xFFFFu), x1 = bf2f(ws[j] >> 16);
        float y0 = fmaxf(fmaf(bn1[c0],     x0, bn1[128 + c0]),     0.f);
        float y1 = fmaxf(fmaf(bn1[c0 + 1], x1, bn1[128 + c0 + 1]), 0.f);
        float4 w2 = *(const float4*)(W2 + c0 * 2);   // rows c0, c0+1 of [128][2]
        acc0 += y0 * w2.x + y1 * w2.z;
        acc1 += y0 * w2.y + y1 * w2.w;
    }
    for (int off = 8; off; off >>= 1) {              // reduce within 16-lane group
        acc0 += __shfl_xor(acc0, off);
        acc1 += __shfl_xor(acc1, off);
    }
    if (q == 0) {
        float dv = dinv[node];
        *(float2*)(h2s + (size_t)node * 2) = make_float2(acc0 * dv, acc1 * dv);
    }
}

// ---------------------------------------------------------------------------
// aggregate2 by gather + fused BN2 stats: thread per node
// ---------------------------------------------------------------------------
__global__ __launch_bounds__(256) void agg2_bn2_k(
    const int* __restrict__ csr, const int* __restrict__ offs,
    const int* __restrict__ cnt, const float* __restrict__ dinv,
    const float* __restrict__ h2s, float* __restrict__ out2,
    float* __restrict__ stats, int N) {
    __shared__ float4 red[256];
    int t = threadIdx.x;
    int node = blockIdx.x * 256 + t;
    float2 o = make_float2(0.f, 0.f);
    if (node < N) {
        int beg = offs[node], num = cnt[node];
        float2 acc = *(const float2*)(h2s + (size_t)node * 2);
        for (int i = 0; i < num; ++i) {
            int s = csr[beg + i];
            float2 v = *(const float2*)(h2s + (size_t)s * 2);
            acc.x += v.x;
            acc.y += v.y;
        }
        float dd = dinv[node];
        o = make_float2(acc.x * dd, acc.y * dd);
        *(float2*)(out2 + (size_t)node * 2) = o;
    }
    red[t] = make_float4(o.x, o.y, o.x * o.x, o.y * o.y);
    __syncthreads();
    for (int s = 128; s; s >>= 1) {
        if (t < s) {
            red[t].x += red[t + s].x; red[t].y += red[t + s].y;
            red[t].z += red[t + s].z; red[t].w += red[t + s].w;
        }
        __syncthreads();
    }
    if (t == 0) {
        atomicAdd(&stats[0], red[0].x); atomicAdd(&stats[1], red[0].y);
        atomicAdd(&stats[2], red[0].z); atomicAdd(&stats[3], red[0].w);
    }
}

// final: BN2 + softmax(2)
__global__ __launch_bounds__(256) void final_k(
    const float* __restrict__ out2, const float* __restrict__ stats,
    const float* __restrict__ gamma2, const float* __restrict__ beta2,
    float* __restrict__ outp, int N, float invN) {
    int i = blockIdx.x * 256 + threadIdx.x;
    if (i >= N) return;
    float m0 = stats[0] * invN, m1 = stats[1] * invN;
    float var0 = stats[2] * invN - m0 * m0;
    float var1 = stats[3] * invN - m1 * m1;
    float a0 = gamma2[0] * rsqrtf(var0 + BN_EPS);
    float a1 = gamma2[1] * rsqrtf(var1 + BN_EPS);
    float c0 = beta2[0] - m0 * a0;
    float c1 = beta2[1] - m1 * a1;
    float2 v = *(const float2*)(out2 + (size_t)i * 2);
    float y0 = fmaf(a0, v.x, c0);
    float y1 = fmaf(a1, v.y, c1);
    float mx = fmaxf(y0, y1);
    float e0 = expf(y0 - mx), e1 = expf(y1 - mx);
    float inv = 1.f / (e0 + e1);
    *(float2*)(outp + (size_t)i * 2) = make_float2(e0 * inv, e1 * inv);
}

// ---------------------------------------------------------------------------
extern "C" void kernel_launch(void* const* d_in, const int* in_sizes, int n_in,
                              void* d_out, int out_size, void* d_ws, size_t ws_size,
                              hipStream_t stream) {
    const int*   edge   = (const int*)d_in[0];
    const float* X      = (const float*)d_in[1];
    const float* uY     = (const float*)d_in[2];
    const float* W1     = (const float*)d_in[3];
    // b1/b2 cancel under BatchNorm -- skipped
    const float* W2     = (const float*)d_in[5];
    const float* gamma1 = (const float*)d_in[7];
    const float* beta1  = (const float*)d_in[8];
    const float* gamma2 = (const float*)d_in[9];
    const float* beta2  = (const float*)d_in[10];

    const int E = in_sizes[0] / 2;
    const int N = in_sizes[1] / 128;
    const int* srcI = edge;
    const int* dstI = edge + E;

    const int nchunk  = (E + CHUNK - 1) / CHUNK;
    const int nbucket = (N + 255) >> BSHIFT;
    const int total   = nbucket * nchunk;
    const int nscan   = (total + 1023) / 1024;   // scan blocks (<=256)

    // workspace layout (4-byte words):
    // stats1[256] bn1[256] stats2[64] Whi[6144w] Wlo[6144w] blksum[256]
    // h1s[N*64] out1[N*64] dinv[N] h2s[2N] out2[2N] cnt[N] offs[N]
    // histT[total+1] pack[E] csr[E]
    float* stats1 = (float*)d_ws;
    float* bn1    = stats1 + 256;
    float* stats2 = bn1 + 256;
    unsigned short* Whi = (unsigned short*)(stats2 + 64);     // 128*192 bf16
    unsigned short* Wlo = Whi + 128 * 192;
    int*   blksum = (int*)(Wlo + 128 * 192);
    unsigned int* h1s  = (unsigned int*)(blksum + 256);
    unsigned int* out1 = h1s + (size_t)N * 64;
    float* dinv   = (float*)(out1 + (size_t)N * 64);
    float* h2s    = dinv + N;
    float* out2   = h2s + (size_t)N * 2;
    int*   cnt    = (int*)(out2 + (size_t)N * 2);
    int*   offs   = cnt + N;
    int*   histT  = offs + N;
    unsigned int* pack = (unsigned int*)(histT + total + 1);
    int*   csr    = (int*)(pack + E);

    hipMemsetAsync(stats1, 0, 256 * sizeof(float), stream);
    hipMemsetAsync(stats2, 0, 4 * sizeof(float), stream);

    // CSR build: histogram -> parallel scan -> partition -> per-bucket sort
    hist_k<<<nchunk, 256, 0, stream>>>(dstI, histT, E, nchunk, nbucket);
    scan_a_k<<<nscan, 256, 0, stream>>>(histT, blksum, total);
    scan_b_k<<<1, 256, 0, stream>>>(blksum, nscan);
    scan_c_k<<<nscan * 4, 256, 0, stream>>>(histT, blksum, total, E);
    partition_k<<<nchunk, 256, 0, stream>>>(srcI, dstI, histT, pack, E, nchunk, nbucket);
    bucket_k<<<nbucket, 256, 0, stream>>>(pack, histT, csr, offs, cnt, dinv, N, nchunk);

    w1cast_k<<<(192 * 128 + 255) / 256, 256, 0, stream>>>(W1, Whi, Wlo);
    gemm1_mfma_k<<<(N + 127) / 128, 256, 0, stream>>>(uY, X, Whi, Wlo, dinv,
                                                      (unsigned short*)h1s, N);
    agg1_gather_k<<<(N + 3) / 4, 256, 0, stream>>>(csr, offs, cnt, dinv, h1s, out1, N);
    bn1_stats_k<<<512, 256, 0, stream>>>(out1, stats1, N);
    bn1_final_k<<<1, 128, 0, stream>>>(stats1, gamma1, beta1, bn1, 1.0f / N);
    gemm2_k<<<(N + 15) / 16, 256, 0, stream>>>(out1, bn1, W2, dinv, h2s, N);
    agg2_bn2_k<<<(N + 255) / 256, 256, 0, stream>>>(csr, offs, cnt, dinv, h2s, out2,
                                                    stats2, N);
    final_k<<<(N + 255) / 256, 256, 0, stream>>>(out2, stats2, gamma2, beta2,
                                                 (float*)d_out, N, 1.0f / N);
}